// Round 1
// baseline (2162.344 us; speedup 1.0000x reference)
//
#include <hip/hip_runtime.h>
#include <math.h>

#define TPB 256

// ---------------- degree / norm ----------------
__global__ void k_fill1(float* __restrict__ p, int n) {
    int i = blockIdx.x * TPB + threadIdx.x;
    if (i < n) p[i] = 1.0f;   // self loop contributes 1 to every degree
}

__global__ void k_degcnt(const int* __restrict__ dst, float* __restrict__ deg, int e) {
    int i = blockIdx.x * TPB + threadIdx.x;
    if (i < e) atomicAdd(&deg[dst[i]], 1.0f);
}

__global__ void k_rsqrt(float* __restrict__ p, int n) {
    int i = blockIdx.x * TPB + threadIdx.x;
    if (i < n) p[i] = rsqrtf(p[i]);
}

__global__ void k_norm(const int* __restrict__ src, const int* __restrict__ dst,
                       const float* __restrict__ dinv, float* __restrict__ nrm, int e) {
    int i = blockIdx.x * TPB + threadIdx.x;
    if (i < e) nrm[i] = dinv[src[i]] * dinv[dst[i]];
}

// ---------------- input matmul: x(N,3) @ W1(3,32) ----------------
__global__ void k_mm_in(const float* __restrict__ x, const float* __restrict__ W,
                        float* __restrict__ T, int n) {
    int t = blockIdx.x * TPB + threadIdx.x;
    if (t >= n * 32) return;
    int i = t >> 5, f = t & 31;
    const float* xr = x + i * 3;
    T[t] = xr[0] * W[f] + xr[1] * W[32 + f] + xr[2] * W[64 + f];
}

// ---------------- AGG init with self-loop term: AGG[i][f] = T[i][f]*dinv[i]^2 ----------------
template <int LOG2F>
__global__ void k_selfinit(const float* __restrict__ T, const float* __restrict__ dinv,
                           float* __restrict__ AGG, int n) {
    int t = blockIdx.x * TPB + threadIdx.x;
    if (t >= (n << LOG2F)) return;
    int i = t >> LOG2F;
    float d = dinv[i];
    AGG[t] = T[t] * d * d;
}

// ---------------- edge scatter: AGG[dst] += T[src]*norm ----------------
template <int LOG2F>
__global__ void k_scatter(const int* __restrict__ src, const int* __restrict__ dst,
                          const float* __restrict__ nrm, const float* __restrict__ dinv,
                          const float* __restrict__ T, float* __restrict__ AGG, int e) {
    const int F = 1 << LOG2F;
    long long t = (long long)blockIdx.x * TPB + threadIdx.x;
    int ei = (int)(t >> LOG2F);
    if (ei >= e) return;
    int f = (int)t & (F - 1);
    int s = src[ei], d = dst[ei];
    float w = nrm ? nrm[ei] : dinv[s] * dinv[d];
    atomicAdd(&AGG[((long long)d << LOG2F) | f], T[((long long)s << LOG2F) | f] * w);
}

// ---------------- fused relu(AGG+b) @ W  ->  T(N,64) ----------------
template <int FIN>
__global__ void k_mm_relu(const float* __restrict__ AGG, const float* __restrict__ b,
                          const float* __restrict__ W, float* __restrict__ T, int n) {
    int t = blockIdx.x * TPB + threadIdx.x;
    if (t >= n * 64) return;
    int i = t >> 6, f = t & 63;
    const float* ar = AGG + (long long)i * FIN;
    float s = 0.0f;
#pragma unroll
    for (int k = 0; k < FIN; k++) {
        float h = ar[k] + b[k];
        h = h > 0.0f ? h : 0.0f;
        s += h * W[k * 64 + f];
    }
    T[t] = s;
}

// ---------------- pool (max & mean per graph) + classifier + softmax ----------------
__global__ void k_pool(const float* __restrict__ AGG, const float* __restrict__ b3,
                       const float* __restrict__ Wc, const float* __restrict__ bc,
                       float* __restrict__ out, int n, int g_total) {
    int g = blockIdx.x;
    int f = threadIdx.x;  // 64 threads, one per feature
    long long start = ((long long)g * n + g_total - 1) / g_total;
    long long end = ((long long)(g + 1) * n + g_total - 1) / g_total;
    float bf = b3[f];
    float mx = -INFINITY, sm = 0.0f;
    for (long long i = start; i < end; i++) {
        float v = AGG[(i << 6) | f] + bf;
        mx = fmaxf(mx, v);
        sm += v;
    }
    __shared__ float smax[64];
    __shared__ float smean[64];
    __shared__ float slog[2];
    long long cnt = end - start;
    smax[f] = mx;
    smean[f] = sm / (float)(cnt > 0 ? cnt : 1);
    __syncthreads();
    if (f < 2) {
        float l = bc[f];
        for (int k = 0; k < 64; k++)
            l += smax[k] * Wc[k * 2 + f] + smean[k] * Wc[(64 + k) * 2 + f];
        slog[f] = l;
    }
    __syncthreads();
    if (f == 0) {
        float m = fmaxf(slog[0], slog[1]);
        float e0 = expf(slog[0] - m), e1 = expf(slog[1] - m);
        float inv = 1.0f / (e0 + e1);
        out[g * 2 + 0] = e0 * inv;
        out[g * 2 + 1] = e1 * inv;
    }
}

extern "C" void kernel_launch(void* const* d_in, const int* in_sizes, int n_in,
                              void* d_out, int out_size, void* d_ws, size_t ws_size,
                              hipStream_t stream) {
    const float* x  = (const float*)d_in[0];
    const float* W1 = (const float*)d_in[1];
    const float* b1 = (const float*)d_in[2];
    const float* W2 = (const float*)d_in[3];
    const float* b2 = (const float*)d_in[4];
    const float* W3 = (const float*)d_in[5];
    const float* b3 = (const float*)d_in[6];
    const float* Wc = (const float*)d_in[7];
    const float* bc = (const float*)d_in[8];
    const int*   ei = (const int*)d_in[9];   // [2, E] (harness passes ints as int32)
    // d_in[10] = batch, derived analytically instead (matches reference construction)

    const int N = in_sizes[0] / 3;
    const int E = in_sizes[9] / 2;
    const int G = out_size / 2;
    const int* src = ei;
    const int* dst = ei + E;

    // workspace layout
    char* ws = (char*)d_ws;
    size_t off = 0;
    auto alloc = [&](size_t bytes) {
        size_t o = off;
        off = (off + bytes + 255) & ~(size_t)255;
        return o;
    };
    size_t o_dinv = alloc((size_t)N * 4);
    size_t o_T    = alloc((size_t)N * 64 * 4);
    size_t o_AGG  = alloc((size_t)N * 64 * 4);
    float* dinv = (float*)(ws + o_dinv);
    float* T    = (float*)(ws + o_T);
    float* AGG  = (float*)(ws + o_AGG);
    float* nrm = nullptr;
    size_t o_nrm = alloc((size_t)E * 4);
    if (off <= ws_size) nrm = (float*)(ws + o_nrm);  // optional: fall back to on-the-fly norm

    auto cdiv = [](long long a, long long b) { return (int)((a + b - 1) / b); };

    // degrees -> dinv
    k_fill1<<<cdiv(N, TPB), TPB, 0, stream>>>(dinv, N);
    k_degcnt<<<cdiv(E, TPB), TPB, 0, stream>>>(dst, dinv, E);
    k_rsqrt<<<cdiv(N, TPB), TPB, 0, stream>>>(dinv, N);
    if (nrm) k_norm<<<cdiv(E, TPB), TPB, 0, stream>>>(src, dst, dinv, nrm, E);

    // layer 1: T = x@W1 (N,32); AGG1 = selfloop + scatter
    k_mm_in<<<cdiv((long long)N * 32, TPB), TPB, 0, stream>>>(x, W1, T, N);
    k_selfinit<5><<<cdiv((long long)N * 32, TPB), TPB, 0, stream>>>(T, dinv, AGG, N);
    k_scatter<5><<<cdiv((long long)E * 32, TPB), TPB, 0, stream>>>(src, dst, nrm, dinv, T, AGG, E);

    // layer 2: T = relu(AGG1+b1)@W2 (N,64)
    k_mm_relu<32><<<cdiv((long long)N * 64, TPB), TPB, 0, stream>>>(AGG, b1, W2, T, N);
    k_selfinit<6><<<cdiv((long long)N * 64, TPB), TPB, 0, stream>>>(T, dinv, AGG, N);
    k_scatter<6><<<cdiv((long long)E * 64, TPB), TPB, 0, stream>>>(src, dst, nrm, dinv, T, AGG, E);

    // layer 3: T = relu(AGG2+b2)@W3 (N,64)
    k_mm_relu<64><<<cdiv((long long)N * 64, TPB), TPB, 0, stream>>>(AGG, b2, W3, T, N);
    k_selfinit<6><<<cdiv((long long)N * 64, TPB), TPB, 0, stream>>>(T, dinv, AGG, N);
    k_scatter<6><<<cdiv((long long)E * 64, TPB), TPB, 0, stream>>>(src, dst, nrm, dinv, T, AGG, E);

    // pool + classify + softmax
    k_pool<<<G, 64, 0, stream>>>(AGG, b3, Wc, bc, (float*)d_out, N, G);
}

// Round 2
// 1111.353 us; speedup vs baseline: 1.9457x; 1.9457x over previous
//
#include <hip/hip_runtime.h>
#include <math.h>

#define TPB 256
#define SCAN_TPB 256
#define SCAN_ELEMS 2048  // 8 per thread

// ---------------- zero / count / dinv ----------------
__global__ void k_zero_i(int* __restrict__ p, int n) {
    int i = blockIdx.x * TPB + threadIdx.x;
    if (i < n) p[i] = 0;
}

__global__ void k_count(const int* __restrict__ dst, int* __restrict__ cnt, int e) {
    int i = blockIdx.x * TPB + threadIdx.x;
    if (i < e) atomicAdd(&cnt[dst[i]], 1);
}

__global__ void k_dinv(const int* __restrict__ cnt, float* __restrict__ dinv, int n) {
    int i = blockIdx.x * TPB + threadIdx.x;
    if (i < n) dinv[i] = rsqrtf((float)(cnt[i] + 1));  // +1 self loop
}

// ---------------- exclusive scan (3 kernels) ----------------
__global__ void k_scan1(const int* __restrict__ cnt, int* __restrict__ out,
                        int* __restrict__ bsums, int n) {
    __shared__ int lds[SCAN_TPB];
    int base = blockIdx.x * SCAN_ELEMS;
    int t = threadIdx.x;
    int v[8];
    int s = 0;
#pragma unroll
    for (int k = 0; k < 8; k++) {
        int idx = base + t * 8 + k;
        v[k] = idx < n ? cnt[idx] : 0;
        s += v[k];
    }
    lds[t] = s;
    __syncthreads();
    for (int d = 1; d < SCAN_TPB; d <<= 1) {
        int x = (t >= d) ? lds[t - d] : 0;
        __syncthreads();
        lds[t] += x;
        __syncthreads();
    }
    int run = (t == 0) ? 0 : lds[t - 1];
    if (t == SCAN_TPB - 1) bsums[blockIdx.x] = lds[SCAN_TPB - 1];
#pragma unroll
    for (int k = 0; k < 8; k++) {
        int idx = base + t * 8 + k;
        if (idx < n) out[idx] = run;
        run += v[k];
    }
}

__global__ void k_scan2(int* __restrict__ bsums, int nb) {
    if (threadIdx.x == 0 && blockIdx.x == 0) {
        int run = 0;
        for (int i = 0; i < nb; i++) { int v = bsums[i]; bsums[i] = run; run += v; }
    }
}

__global__ void k_scan3(int* __restrict__ out, const int* __restrict__ bsums, int n, int e_total) {
    int i = blockIdx.x * TPB + threadIdx.x;
    if (i < n) out[i] += bsums[i / SCAN_ELEMS];
    if (i == n) out[n] = e_total;  // sentinel (grid covers n+1)
}

// ---------------- CSR fill: group edges by dst ----------------
__global__ void k_csr_fill(const int* __restrict__ src, const int* __restrict__ dst,
                           const int* __restrict__ off, int* __restrict__ cur,
                           int* __restrict__ csr, int e) {
    int i = blockIdx.x * TPB + threadIdx.x;
    if (i >= e) return;
    int d = dst[i];
    int pos = off[d] + atomicAdd(&cur[d], 1);
    csr[pos] = src[i];
}

// ---------------- input matmul: x(N,3) @ W1(3,32) ----------------
__global__ void k_mm_in(const float* __restrict__ x, const float* __restrict__ W,
                        float* __restrict__ T, int n) {
    int t = blockIdx.x * TPB + threadIdx.x;
    if (t >= n * 32) return;
    int i = t >> 5, f = t & 31;
    const float* xr = x + i * 3;
    T[t] = xr[0] * W[f] + xr[1] * W[32 + f] + xr[2] * W[64 + f];
}

// ---------------- gather aggregation, F=64: one wave per node ----------------
__global__ void k_gather64(const int* __restrict__ off, const int* __restrict__ csr,
                           const float* __restrict__ dinv, const float* __restrict__ T,
                           float* __restrict__ AGG, int n) {
    int w = (blockIdx.x * TPB + threadIdx.x) >> 6;  // node = global wave id
    if (w >= n) return;
    int f = threadIdx.x & 63;
    float di = dinv[w];
    float acc = T[(w << 6) | f] * di * di;  // self loop
    int e = off[w], e1 = off[w + 1];
    for (; e + 1 < e1; e += 2) {
        int s0 = csr[e], s1 = csr[e + 1];
        float w0 = dinv[s0] * di, w1 = dinv[s1] * di;
        acc += T[(s0 << 6) | f] * w0;
        acc += T[(s1 << 6) | f] * w1;
    }
    if (e < e1) {
        int s = csr[e];
        acc += T[(s << 6) | f] * (dinv[s] * di);
    }
    AGG[(w << 6) | f] = acc;
}

// ---------------- gather aggregation, F=32: one wave per node, 2 edges/iter ----------------
__global__ void k_gather32(const int* __restrict__ off, const int* __restrict__ csr,
                           const float* __restrict__ dinv, const float* __restrict__ T,
                           float* __restrict__ AGG, int n) {
    int w = (blockIdx.x * TPB + threadIdx.x) >> 6;
    if (w >= n) return;
    int lane = threadIdx.x & 63;
    int f = lane & 31, half = lane >> 5;
    float di = dinv[w];
    float acc = (half == 0) ? T[(w << 5) | f] * di * di : 0.0f;
    int e0 = off[w], e1 = off[w + 1];
    for (int e = e0 + half; e < e1; e += 2) {
        int s = csr[e];
        acc += T[(s << 5) | f] * (dinv[s] * di);
    }
    acc += __shfl_xor(acc, 32);
    if (half == 0) AGG[(w << 5) | f] = acc;
}

// ---------------- fused relu(AGG+b) @ W  ->  T(N,64) ----------------
template <int FIN>
__global__ void k_mm_relu(const float* __restrict__ AGG, const float* __restrict__ b,
                          const float* __restrict__ W, float* __restrict__ T, int n) {
    int t = blockIdx.x * TPB + threadIdx.x;
    if (t >= n * 64) return;
    int i = t >> 6, f = t & 63;
    const float* ar = AGG + (long long)i * FIN;
    float s = 0.0f;
#pragma unroll
    for (int k = 0; k < FIN; k++) {
        float h = ar[k] + b[k];
        h = h > 0.0f ? h : 0.0f;
        s += h * W[k * 64 + f];
    }
    T[t] = s;
}

// ---------------- pool (max & mean per graph) + classifier + softmax ----------------
__global__ void k_pool(const float* __restrict__ AGG, const float* __restrict__ b3,
                       const float* __restrict__ Wc, const float* __restrict__ bc,
                       float* __restrict__ out, int n, int g_total) {
    int g = blockIdx.x;
    int f = threadIdx.x;  // 64 threads, one per feature
    long long start = ((long long)g * n + g_total - 1) / g_total;
    long long end = ((long long)(g + 1) * n + g_total - 1) / g_total;
    float bf = b3[f];
    float mx = -INFINITY, sm = 0.0f;
    for (long long i = start; i < end; i++) {
        float v = AGG[(i << 6) | f] + bf;
        mx = fmaxf(mx, v);
        sm += v;
    }
    __shared__ float smax[64];
    __shared__ float smean[64];
    __shared__ float slog[2];
    long long cnt = end - start;
    smax[f] = mx;
    smean[f] = sm / (float)(cnt > 0 ? cnt : 1);
    __syncthreads();
    if (f < 2) {
        float l = bc[f];
        for (int k = 0; k < 64; k++)
            l += smax[k] * Wc[k * 2 + f] + smean[k] * Wc[(64 + k) * 2 + f];
        slog[f] = l;
    }
    __syncthreads();
    if (f == 0) {
        float m = fmaxf(slog[0], slog[1]);
        float e0 = expf(slog[0] - m), e1 = expf(slog[1] - m);
        float inv = 1.0f / (e0 + e1);
        out[g * 2 + 0] = e0 * inv;
        out[g * 2 + 1] = e1 * inv;
    }
}

extern "C" void kernel_launch(void* const* d_in, const int* in_sizes, int n_in,
                              void* d_out, int out_size, void* d_ws, size_t ws_size,
                              hipStream_t stream) {
    const float* x  = (const float*)d_in[0];
    const float* W1 = (const float*)d_in[1];
    const float* b1 = (const float*)d_in[2];
    const float* W2 = (const float*)d_in[3];
    const float* b2 = (const float*)d_in[4];
    const float* W3 = (const float*)d_in[5];
    const float* b3 = (const float*)d_in[6];
    const float* Wc = (const float*)d_in[7];
    const float* bc = (const float*)d_in[8];
    const int*   ei = (const int*)d_in[9];

    const int N = in_sizes[0] / 3;
    const int E = in_sizes[9] / 2;
    const int G = out_size / 2;
    const int* src = ei;
    const int* dst = ei + E;

    // workspace layout
    char* ws = (char*)d_ws;
    size_t off_b = 0;
    auto alloc = [&](size_t bytes) {
        size_t o = off_b;
        off_b = (off_b + bytes + 255) & ~(size_t)255;
        return (void*)(ws + o);
    };
    float* dinv  = (float*)alloc((size_t)N * 4);
    int*   cnt   = (int*)alloc((size_t)N * 4);       // also used as cursor
    int*   off   = (int*)alloc((size_t)(N + 1) * 4);
    int*   bsums = (int*)alloc(256 * 4);
    int*   csr   = (int*)alloc((size_t)E * 4);
    float* T     = (float*)alloc((size_t)N * 64 * 4);
    float* AGG   = (float*)alloc((size_t)N * 64 * 4);

    auto cdiv = [](long long a, long long b) { return (int)((a + b - 1) / b); };
    const int nscan = cdiv(N, SCAN_ELEMS);

    // ---- graph prep: counts -> dinv, offsets; CSR fill ----
    k_zero_i<<<cdiv(N, TPB), TPB, 0, stream>>>(cnt, N);
    k_count<<<cdiv(E, TPB), TPB, 0, stream>>>(dst, cnt, E);
    k_dinv<<<cdiv(N, TPB), TPB, 0, stream>>>(cnt, dinv, N);
    k_scan1<<<nscan, SCAN_TPB, 0, stream>>>(cnt, off, bsums, N);
    k_scan2<<<1, 64, 0, stream>>>(bsums, nscan);
    k_scan3<<<cdiv(N + 1, TPB), TPB, 0, stream>>>(off, bsums, N, E);
    k_zero_i<<<cdiv(N, TPB), TPB, 0, stream>>>(cnt, N);  // reuse as cursor
    k_csr_fill<<<cdiv(E, TPB), TPB, 0, stream>>>(src, dst, off, cnt, csr, E);

    // ---- layer 1: T = x@W1 (N,32); AGG = gather ----
    k_mm_in<<<cdiv((long long)N * 32, TPB), TPB, 0, stream>>>(x, W1, T, N);
    k_gather32<<<cdiv(N, 4), TPB, 0, stream>>>(off, csr, dinv, T, AGG, N);

    // ---- layer 2: T = relu(AGG+b1)@W2 (N,64); AGG = gather ----
    k_mm_relu<32><<<cdiv((long long)N * 64, TPB), TPB, 0, stream>>>(AGG, b1, W2, T, N);
    k_gather64<<<cdiv(N, 4), TPB, 0, stream>>>(off, csr, dinv, T, AGG, N);

    // ---- layer 3: T = relu(AGG+b2)@W3 (N,64); AGG = gather ----
    k_mm_relu<64><<<cdiv((long long)N * 64, TPB), TPB, 0, stream>>>(AGG, b2, W3, T, N);
    k_gather64<<<cdiv(N, 4), TPB, 0, stream>>>(off, csr, dinv, T, AGG, N);

    // ---- pool + classify + softmax ----
    k_pool<<<G, 64, 0, stream>>>(AGG, b3, Wc, bc, (float*)d_out, N, G);
}

// Round 3
// 775.201 us; speedup vs baseline: 2.7894x; 1.4336x over previous
//
#include <hip/hip_runtime.h>
#include <math.h>

#define TPB 256
#define SCAN_TPB 256
#define SCAN_ELEMS 2048  // 8 per thread

__device__ inline float bf2f(unsigned int u16) {
    return __uint_as_float(u16 << 16);
}
__device__ inline unsigned short f2bf(float f) {
    unsigned int x = __float_as_uint(f);
    return (unsigned short)((x + 0x7fffu + ((x >> 16) & 1u)) >> 16);  // RNE
}

// ---------------- prep: zero / count / dinv ----------------
__global__ void k_zero_i(int* __restrict__ p, int n) {
    int i = blockIdx.x * TPB + threadIdx.x;
    if (i < n) p[i] = 0;
}

__global__ void k_count(const int* __restrict__ dst, int* __restrict__ cnt, int e) {
    int i = blockIdx.x * TPB + threadIdx.x;
    if (i < e) atomicAdd(&cnt[dst[i]], 1);
}

__global__ void k_dinv(const int* __restrict__ cnt, float* __restrict__ dinv, int n) {
    int i = blockIdx.x * TPB + threadIdx.x;
    if (i < n) dinv[i] = rsqrtf((float)(cnt[i] + 1));  // +1 self loop
}

// ---------------- exclusive scan ----------------
__global__ void k_scan1(const int* __restrict__ cnt, int* __restrict__ out,
                        int* __restrict__ bsums, int n) {
    __shared__ int lds[SCAN_TPB];
    int base = blockIdx.x * SCAN_ELEMS;
    int t = threadIdx.x;
    int v[8];
    int s = 0;
#pragma unroll
    for (int k = 0; k < 8; k++) {
        int idx = base + t * 8 + k;
        v[k] = idx < n ? cnt[idx] : 0;
        s += v[k];
    }
    lds[t] = s;
    __syncthreads();
    for (int d = 1; d < SCAN_TPB; d <<= 1) {
        int x = (t >= d) ? lds[t - d] : 0;
        __syncthreads();
        lds[t] += x;
        __syncthreads();
    }
    int run = (t == 0) ? 0 : lds[t - 1];
    if (t == SCAN_TPB - 1) bsums[blockIdx.x] = lds[SCAN_TPB - 1];
#pragma unroll
    for (int k = 0; k < 8; k++) {
        int idx = base + t * 8 + k;
        if (idx < n) out[idx] = run;
        run += v[k];
    }
}

__global__ void k_scan2(int* __restrict__ bsums, int nb) {
    if (threadIdx.x == 0 && blockIdx.x == 0) {
        int run = 0;
        for (int i = 0; i < nb; i++) { int v = bsums[i]; bsums[i] = run; run += v; }
    }
}

__global__ void k_scan3(int* __restrict__ out, const int* __restrict__ bsums, int n, int e_total) {
    int i = blockIdx.x * TPB + threadIdx.x;
    if (i < n) out[i] += bsums[i / SCAN_ELEMS];
    if (i == n) out[n] = e_total;
}

// ---------------- CSR fill ----------------
__global__ void k_csr_fill(const int* __restrict__ src, const int* __restrict__ dst,
                           const int* __restrict__ off, int* __restrict__ cur,
                           int* __restrict__ csr, int e) {
    int i = blockIdx.x * TPB + threadIdx.x;
    if (i >= e) return;
    int d = dst[i];
    int pos = off[d] + atomicAdd(&cur[d], 1);
    csr[pos] = src[i];
}

// ---------------- gather x (F=3): Xa = S*x, thread per node ----------------
__global__ void k_gather3(const int* __restrict__ off, const int* __restrict__ csr,
                          const float* __restrict__ dinv, const float* __restrict__ x,
                          float* __restrict__ Xa, int n) {
    int i = blockIdx.x * TPB + threadIdx.x;
    if (i >= n) return;
    float di = dinv[i];
    float ww = di * di;
    float a0 = x[i * 3] * ww, a1 = x[i * 3 + 1] * ww, a2 = x[i * 3 + 2] * ww;
    int e1 = off[i + 1];
    for (int e = off[i]; e < e1; ++e) {
        int s = csr[e];
        float w = dinv[s] * di;
        a0 += x[s * 3] * w;
        a1 += x[s * 3 + 1] * w;
        a2 += x[s * 3 + 2] * w;
    }
    Xa[i * 3] = a0; Xa[i * 3 + 1] = a1; Xa[i * 3 + 2] = a2;
}

// ---------------- h1 = relu(Xa@W1 + b1) -> bf16 ----------------
__global__ void k_mm1(const float* __restrict__ Xa, const float* __restrict__ W,
                      const float* __restrict__ b, unsigned short* __restrict__ T, int n) {
    int t = blockIdx.x * TPB + threadIdx.x;
    if (t >= n * 32) return;
    int i = t >> 5, f = t & 31;
    const float* xr = Xa + i * 3;
    float h = xr[0] * W[f] + xr[1] * W[32 + f] + xr[2] * W[64 + f] + b[f];
    T[t] = f2bf(fmaxf(h, 0.0f));
}

// ---------------- gather F=32 bf16: 8 lanes/edge, 8 edges in flight ----------------
__global__ void k_gather32b(const int* __restrict__ off, const int* __restrict__ csr,
                            const float* __restrict__ dinv, const unsigned short* __restrict__ T,
                            float* __restrict__ G, int n) {
    int w = (blockIdx.x * TPB + threadIdx.x) >> 6;
    if (w >= n) return;
    int lane = threadIdx.x & 63;
    int grp = lane >> 3, q = lane & 7;   // feats 4q..4q+3
    float di = dinv[w];
    float a0 = 0, a1 = 0, a2 = 0, a3 = 0;
    if (grp == 0) {
        uint2 v = *(const uint2*)(T + (size_t)w * 32 + q * 4);
        float ww = di * di;
        a0 = bf2f(v.x & 0xffff) * ww; a1 = bf2f(v.x >> 16) * ww;
        a2 = bf2f(v.y & 0xffff) * ww; a3 = bf2f(v.y >> 16) * ww;
    }
    int e1 = off[w + 1];
    for (int e = off[w] + grp; e < e1; e += 8) {
        int s = csr[e];
        float ww = dinv[s] * di;
        uint2 v = *(const uint2*)(T + (size_t)s * 32 + q * 4);
        a0 += bf2f(v.x & 0xffff) * ww; a1 += bf2f(v.x >> 16) * ww;
        a2 += bf2f(v.y & 0xffff) * ww; a3 += bf2f(v.y >> 16) * ww;
    }
#pragma unroll
    for (int m = 8; m < 64; m <<= 1) {
        a0 += __shfl_xor(a0, m); a1 += __shfl_xor(a1, m);
        a2 += __shfl_xor(a2, m); a3 += __shfl_xor(a3, m);
    }
    if (grp == 0) *(float4*)(G + (size_t)w * 32 + q * 4) = make_float4(a0, a1, a2, a3);
}

// ---------------- h2 = relu(G1@W2 + b2) -> bf16 (32 -> 64) ----------------
__global__ void k_mm2(const float* __restrict__ G, const float* __restrict__ W,
                      const float* __restrict__ b, unsigned short* __restrict__ T, int n) {
    int t = blockIdx.x * TPB + threadIdx.x;
    if (t >= n * 64) return;
    int i = t >> 6, f = t & 63;
    const float* gr = G + (size_t)i * 32;
    float s = b[f];
#pragma unroll
    for (int k = 0; k < 32; k++) s += gr[k] * W[k * 64 + f];
    T[t] = f2bf(fmaxf(s, 0.0f));
}

// ---------------- gather F=64 bf16: 16 lanes/edge, 4 edges in flight ----------------
__global__ void k_gather64b(const int* __restrict__ off, const int* __restrict__ csr,
                            const float* __restrict__ dinv, const unsigned short* __restrict__ T,
                            float* __restrict__ G, int n) {
    int w = (blockIdx.x * TPB + threadIdx.x) >> 6;
    if (w >= n) return;
    int lane = threadIdx.x & 63;
    int grp = lane >> 4, q = lane & 15;  // feats 4q..4q+3
    float di = dinv[w];
    float a0 = 0, a1 = 0, a2 = 0, a3 = 0;
    if (grp == 0) {
        uint2 v = *(const uint2*)(T + (size_t)w * 64 + q * 4);
        float ww = di * di;
        a0 = bf2f(v.x & 0xffff) * ww; a1 = bf2f(v.x >> 16) * ww;
        a2 = bf2f(v.y & 0xffff) * ww; a3 = bf2f(v.y >> 16) * ww;
    }
    int e1 = off[w + 1];
    for (int e = off[w] + grp; e < e1; e += 4) {
        int s = csr[e];
        float ww = dinv[s] * di;
        uint2 v = *(const uint2*)(T + (size_t)s * 64 + q * 4);
        a0 += bf2f(v.x & 0xffff) * ww; a1 += bf2f(v.x >> 16) * ww;
        a2 += bf2f(v.y & 0xffff) * ww; a3 += bf2f(v.y >> 16) * ww;
    }
    a0 += __shfl_xor(a0, 16); a1 += __shfl_xor(a1, 16);
    a2 += __shfl_xor(a2, 16); a3 += __shfl_xor(a3, 16);
    a0 += __shfl_xor(a0, 32); a1 += __shfl_xor(a1, 32);
    a2 += __shfl_xor(a2, 32); a3 += __shfl_xor(a3, 32);
    if (grp == 0) *(float4*)(G + (size_t)w * 64 + q * 4) = make_float4(a0, a1, a2, a3);
}

// ---------------- h3 = G2@W3 + b3 -> fp32 (64 -> 64, no relu) ----------------
__global__ void k_mm3(const float* __restrict__ G, const float* __restrict__ W,
                      const float* __restrict__ b, float* __restrict__ H, int n) {
    int t = blockIdx.x * TPB + threadIdx.x;
    if (t >= n * 64) return;
    int i = t >> 6, f = t & 63;
    const float* gr = G + (size_t)i * 64;
    float s = b[f];
#pragma unroll
    for (int k = 0; k < 64; k++) s += gr[k] * W[k * 64 + f];
    H[t] = s;
}

// ---------------- pool (max & mean per graph) + classifier + softmax ----------------
__global__ void k_pool(const float* __restrict__ H, const float* __restrict__ Wc,
                       const float* __restrict__ bc, float* __restrict__ out,
                       int n, int g_total) {
    int g = blockIdx.x;
    int f = threadIdx.x & 63;
    int c = threadIdx.x >> 6;  // 0..3 chunks
    long long start = ((long long)g * n + g_total - 1) / g_total;
    long long end = ((long long)(g + 1) * n + g_total - 1) / g_total;
    float mx = -INFINITY, sm = 0.0f;
    for (long long i = start + c; i < end; i += 4) {
        float v = H[(i << 6) | f];
        mx = fmaxf(mx, v);
        sm += v;
    }
    __shared__ float smax[4][64], ssum[4][64], slog[2];
    smax[c][f] = mx; ssum[c][f] = sm;
    __syncthreads();
    if (c == 0) {
        mx = fmaxf(fmaxf(smax[0][f], smax[1][f]), fmaxf(smax[2][f], smax[3][f]));
        sm = ssum[0][f] + ssum[1][f] + ssum[2][f] + ssum[3][f];
        long long cnt = end - start;
        smax[0][f] = mx;
        ssum[0][f] = sm / (float)(cnt > 0 ? cnt : 1);
    }
    __syncthreads();
    if (threadIdx.x < 2) {
        int cls = threadIdx.x;
        float l = bc[cls];
        for (int k = 0; k < 64; k++)
            l += smax[0][k] * Wc[k * 2 + cls] + ssum[0][k] * Wc[(64 + k) * 2 + cls];
        slog[cls] = l;
    }
    __syncthreads();
    if (threadIdx.x == 0) {
        float m = fmaxf(slog[0], slog[1]);
        float e0 = expf(slog[0] - m), e1 = expf(slog[1] - m);
        float inv = 1.0f / (e0 + e1);
        out[g * 2 + 0] = e0 * inv;
        out[g * 2 + 1] = e1 * inv;
    }
}

extern "C" void kernel_launch(void* const* d_in, const int* in_sizes, int n_in,
                              void* d_out, int out_size, void* d_ws, size_t ws_size,
                              hipStream_t stream) {
    const float* x  = (const float*)d_in[0];
    const float* W1 = (const float*)d_in[1];
    const float* b1 = (const float*)d_in[2];
    const float* W2 = (const float*)d_in[3];
    const float* b2 = (const float*)d_in[4];
    const float* W3 = (const float*)d_in[5];
    const float* b3 = (const float*)d_in[6];
    const float* Wc = (const float*)d_in[7];
    const float* bc = (const float*)d_in[8];
    const int*   ei = (const int*)d_in[9];

    const int N = in_sizes[0] / 3;
    const int E = in_sizes[9] / 2;
    const int G = out_size / 2;
    const int* src = ei;
    const int* dst = ei + E;

    char* ws = (char*)d_ws;
    size_t off_b = 0;
    auto alloc = [&](size_t bytes) {
        size_t o = off_b;
        off_b = (off_b + bytes + 255) & ~(size_t)255;
        return (void*)(ws + o);
    };
    float* dinv  = (float*)alloc((size_t)N * 4);
    int*   cnt   = (int*)alloc((size_t)N * 4);
    int*   off   = (int*)alloc((size_t)(N + 1) * 4);
    int*   bsums = (int*)alloc(256 * 4);
    int*   csr   = (int*)alloc((size_t)E * 4);
    float* bufA  = (float*)alloc((size_t)N * 64 * 4);  // Xa -> G1 -> G2
    float* bufB  = (float*)alloc((size_t)N * 64 * 4);  // T1 -> T2 -> H

    float* Xa = bufA;
    unsigned short* T1 = (unsigned short*)bufB;
    float* G1 = bufA;
    unsigned short* T2 = (unsigned short*)bufB;
    float* G2 = bufA;
    float* H  = bufB;

    auto cdiv = [](long long a, long long b) { return (int)((a + b - 1) / b); };
    const int nscan = cdiv(N, SCAN_ELEMS);

    // ---- graph prep ----
    k_zero_i<<<cdiv(N, TPB), TPB, 0, stream>>>(cnt, N);
    k_count<<<cdiv(E, TPB), TPB, 0, stream>>>(dst, cnt, E);
    k_dinv<<<cdiv(N, TPB), TPB, 0, stream>>>(cnt, dinv, N);
    k_scan1<<<nscan, SCAN_TPB, 0, stream>>>(cnt, off, bsums, N);
    k_scan2<<<1, 64, 0, stream>>>(bsums, nscan);
    k_scan3<<<cdiv(N + 1, TPB), TPB, 0, stream>>>(off, bsums, N, E);
    k_zero_i<<<cdiv(N, TPB), TPB, 0, stream>>>(cnt, N);
    k_csr_fill<<<cdiv(E, TPB), TPB, 0, stream>>>(src, dst, off, cnt, csr, E);

    // ---- layer 1: Xa = S*x (F=3); h1 = relu(Xa@W1+b1) bf16 ----
    k_gather3<<<cdiv(N, TPB), TPB, 0, stream>>>(off, csr, dinv, x, Xa, N);
    k_mm1<<<cdiv((long long)N * 32, TPB), TPB, 0, stream>>>(Xa, W1, b1, T1, N);

    // ---- layer 2: G1 = S*h1 (F=32 bf16); h2 = relu(G1@W2+b2) bf16 ----
    k_gather32b<<<cdiv((long long)N * 64, TPB), TPB, 0, stream>>>(off, csr, dinv, T1, G1, N);
    k_mm2<<<cdiv((long long)N * 64, TPB), TPB, 0, stream>>>(G1, W2, b2, T2, N);

    // ---- layer 3: G2 = S*h2 (F=64 bf16); h3 = G2@W3+b3 fp32 ----
    k_gather64b<<<cdiv((long long)N * 64, TPB), TPB, 0, stream>>>(off, csr, dinv, T2, G2, N);
    k_mm3<<<cdiv((long long)N * 64, TPB), TPB, 0, stream>>>(G2, W3, b3, H, N);

    // ---- pool + classify + softmax ----
    k_pool<<<G, TPB, 0, stream>>>(H, Wc, bc, (float*)d_out, N, G);
}

// Round 4
// 537.713 us; speedup vs baseline: 4.0214x; 1.4417x over previous
//
#include <hip/hip_runtime.h>
#include <math.h>

#define TPB 256
#define NB_MAX 512      // coarse buckets of 256 nodes -> supports N <= 131072
#define BKT_SHIFT 8
#define BKT_NODES 256
#define BIN_CHUNK 8192

__device__ inline float bf2f(unsigned int u16) {
    return __uint_as_float(u16 << 16);
}
__device__ inline unsigned short f2bf(float f) {
    unsigned int x = __float_as_uint(f);
    return (unsigned short)((x + 0x7fffu + ((x >> 16) & 1u)) >> 16);  // RNE
}

// ---------------- misc ----------------
__global__ void k_zero_i(int* __restrict__ p, int n) {
    int i = blockIdx.x * TPB + threadIdx.x;
    if (i < n) p[i] = 0;
}

// ---------------- pass A: coarse bucket histogram (LDS) ----------------
__global__ void k_hist_coarse(const int* __restrict__ dst, int* __restrict__ bucketCnt,
                              int e, int nb) {
    __shared__ int h[NB_MAX];
    for (int i = threadIdx.x; i < nb; i += TPB) h[i] = 0;
    __syncthreads();
    for (long long i = (long long)blockIdx.x * TPB + threadIdx.x; i < e;
         i += (long long)gridDim.x * TPB)
        atomicAdd(&h[dst[(int)i] >> BKT_SHIFT], 1);
    __syncthreads();
    for (int i = threadIdx.x; i < nb; i += TPB)
        if (h[i]) atomicAdd(&bucketCnt[i], h[i]);
}

// ---------------- scan buckets (tiny, 1 block) ----------------
__global__ void k_scan_buckets(const int* __restrict__ bucketCnt, int* __restrict__ bucketOff,
                               int* __restrict__ bucketCur, int* __restrict__ off_nodes,
                               int nb, int e, int n) {
    if (threadIdx.x == 0) {
        int run = 0;
        for (int i = 0; i < nb; i++) { bucketOff[i] = run; run += bucketCnt[i]; }
        bucketOff[nb] = run;   // == e
        off_nodes[n] = e;      // CSR sentinel
    }
    __syncthreads();
    for (int i = threadIdx.x; i < nb; i += blockDim.x) bucketCur[i] = bucketOff[i];
}

// ---------------- pass B: bin (src,dst) pairs by coarse bucket ----------------
__global__ void k_bin_pairs(const int* __restrict__ src, const int* __restrict__ dst,
                            int* __restrict__ bucketCur, uint2* __restrict__ pairs,
                            int e, int nb) {
    __shared__ int h[NB_MAX];
    __shared__ int base[NB_MAX];
    int e0 = blockIdx.x * BIN_CHUNK;
    int e1 = min(e0 + BIN_CHUNK, e);
    for (int i = threadIdx.x; i < nb; i += TPB) h[i] = 0;
    __syncthreads();
    for (int i = e0 + threadIdx.x; i < e1; i += TPB)
        atomicAdd(&h[dst[i] >> BKT_SHIFT], 1);
    __syncthreads();
    for (int i = threadIdx.x; i < nb; i += TPB) {
        int c = h[i];
        base[i] = c ? atomicAdd(&bucketCur[i], c) : 0;
        h[i] = 0;  // reuse as intra-block cursor
    }
    __syncthreads();
    for (int i = e0 + threadIdx.x; i < e1; i += TPB) {
        int d = dst[i];
        int b = d >> BKT_SHIFT;
        int pos = base[b] + atomicAdd(&h[b], 1);
        pairs[pos] = make_uint2((unsigned)src[i], (unsigned)d);
    }
}

// ---------------- pass C: per-bucket fine CSR + node offsets + dinv ----------------
__global__ void k_bucket_csr(const uint2* __restrict__ pairs, const int* __restrict__ bucketOff,
                             int* __restrict__ off_nodes, float* __restrict__ dinv,
                             int* __restrict__ csr, int n) {
    __shared__ int hist[BKT_NODES];
    __shared__ int offl[BKT_NODES];
    __shared__ int cur[BKT_NODES];
    int b = blockIdx.x;
    int t = threadIdx.x;  // 256 threads
    int e0 = bucketOff[b], e1 = bucketOff[b + 1];
    int nbase = b << BKT_SHIFT;
    hist[t] = 0;
    __syncthreads();
    for (int e = e0 + t; e < e1; e += BKT_NODES)
        atomicAdd(&hist[(int)pairs[e].y - nbase], 1);
    __syncthreads();
    int v = hist[t];
    offl[t] = v;
    __syncthreads();
    for (int d = 1; d < BKT_NODES; d <<= 1) {
        int x = (t >= d) ? offl[t - d] : 0;
        __syncthreads();
        offl[t] += x;
        __syncthreads();
    }
    int excl = offl[t] - v;
    cur[t] = excl;
    int nd = nbase + t;
    if (nd < n) {
        off_nodes[nd] = e0 + excl;
        dinv[nd] = rsqrtf((float)(v + 1));  // +1 self loop
    }
    __syncthreads();
    for (int e = e0 + t; e < e1; e += BKT_NODES) {
        uint2 p = pairs[e];
        int l = (int)p.y - nbase;
        int pos = e0 + atomicAdd(&cur[l], 1);
        csr[pos] = (int)p.x;
    }
}

// ---------------- gather x (F=3): Xa = S*x, thread per node ----------------
__global__ void k_gather3(const int* __restrict__ off, const int* __restrict__ csr,
                          const float* __restrict__ dinv, const float* __restrict__ x,
                          float* __restrict__ Xa, int n) {
    int i = blockIdx.x * TPB + threadIdx.x;
    if (i >= n) return;
    float di = dinv[i];
    float ww = di * di;
    float a0 = x[i * 3] * ww, a1 = x[i * 3 + 1] * ww, a2 = x[i * 3 + 2] * ww;
    int e1 = off[i + 1];
    for (int e = off[i]; e < e1; ++e) {
        int s = csr[e];
        float w = dinv[s] * di;
        a0 += x[s * 3] * w;
        a1 += x[s * 3 + 1] * w;
        a2 += x[s * 3 + 2] * w;
    }
    Xa[i * 3] = a0; Xa[i * 3 + 1] = a1; Xa[i * 3 + 2] = a2;
}

// ---------------- h1 = relu(Xa@W1 + b1) -> bf16 ----------------
__global__ void k_mm1(const float* __restrict__ Xa, const float* __restrict__ W,
                      const float* __restrict__ b, unsigned short* __restrict__ T, int n) {
    int t = blockIdx.x * TPB + threadIdx.x;
    if (t >= n * 32) return;
    int i = t >> 5, f = t & 31;
    const float* xr = Xa + i * 3;
    float h = xr[0] * W[f] + xr[1] * W[32 + f] + xr[2] * W[64 + f] + b[f];
    T[t] = f2bf(fmaxf(h, 0.0f));
}

// ---------------- gather F=32 bf16: 8 lanes/edge, 8 edges in flight ----------------
__global__ void k_gather32b(const int* __restrict__ off, const int* __restrict__ csr,
                            const float* __restrict__ dinv, const unsigned short* __restrict__ T,
                            float* __restrict__ G, int n) {
    int w = (blockIdx.x * TPB + threadIdx.x) >> 6;
    if (w >= n) return;
    int lane = threadIdx.x & 63;
    int grp = lane >> 3, q = lane & 7;   // feats 4q..4q+3
    float di = dinv[w];
    float a0 = 0, a1 = 0, a2 = 0, a3 = 0;
    if (grp == 0) {
        uint2 v = *(const uint2*)(T + (size_t)w * 32 + q * 4);
        float ww = di * di;
        a0 = bf2f(v.x & 0xffff) * ww; a1 = bf2f(v.x >> 16) * ww;
        a2 = bf2f(v.y & 0xffff) * ww; a3 = bf2f(v.y >> 16) * ww;
    }
    int e1 = off[w + 1];
    for (int e = off[w] + grp; e < e1; e += 8) {
        int s = csr[e];
        float ww = dinv[s] * di;
        uint2 v = *(const uint2*)(T + (size_t)s * 32 + q * 4);
        a0 += bf2f(v.x & 0xffff) * ww; a1 += bf2f(v.x >> 16) * ww;
        a2 += bf2f(v.y & 0xffff) * ww; a3 += bf2f(v.y >> 16) * ww;
    }
#pragma unroll
    for (int m = 8; m < 64; m <<= 1) {
        a0 += __shfl_xor(a0, m); a1 += __shfl_xor(a1, m);
        a2 += __shfl_xor(a2, m); a3 += __shfl_xor(a3, m);
    }
    if (grp == 0) *(float4*)(G + (size_t)w * 32 + q * 4) = make_float4(a0, a1, a2, a3);
}

// ---------------- h2 = relu(G1@W2 + b2) -> bf16 (32 -> 64) ----------------
__global__ void k_mm2(const float* __restrict__ G, const float* __restrict__ W,
                      const float* __restrict__ b, unsigned short* __restrict__ T, int n) {
    int t = blockIdx.x * TPB + threadIdx.x;
    if (t >= n * 64) return;
    int i = t >> 6, f = t & 63;
    const float* gr = G + (size_t)i * 32;
    float s = b[f];
#pragma unroll
    for (int k = 0; k < 32; k++) s += gr[k] * W[k * 64 + f];
    T[t] = f2bf(fmaxf(s, 0.0f));
}

// ---------------- gather F=64 bf16: 16 lanes/edge, 4 edges in flight ----------------
__global__ void k_gather64b(const int* __restrict__ off, const int* __restrict__ csr,
                            const float* __restrict__ dinv, const unsigned short* __restrict__ T,
                            float* __restrict__ G, int n) {
    int w = (blockIdx.x * TPB + threadIdx.x) >> 6;
    if (w >= n) return;
    int lane = threadIdx.x & 63;
    int grp = lane >> 4, q = lane & 15;  // feats 4q..4q+3
    float di = dinv[w];
    float a0 = 0, a1 = 0, a2 = 0, a3 = 0;
    if (grp == 0) {
        uint2 v = *(const uint2*)(T + (size_t)w * 64 + q * 4);
        float ww = di * di;
        a0 = bf2f(v.x & 0xffff) * ww; a1 = bf2f(v.x >> 16) * ww;
        a2 = bf2f(v.y & 0xffff) * ww; a3 = bf2f(v.y >> 16) * ww;
    }
    int e1 = off[w + 1];
    for (int e = off[w] + grp; e < e1; e += 4) {
        int s = csr[e];
        float ww = dinv[s] * di;
        uint2 v = *(const uint2*)(T + (size_t)s * 64 + q * 4);
        a0 += bf2f(v.x & 0xffff) * ww; a1 += bf2f(v.x >> 16) * ww;
        a2 += bf2f(v.y & 0xffff) * ww; a3 += bf2f(v.y >> 16) * ww;
    }
    a0 += __shfl_xor(a0, 16); a1 += __shfl_xor(a1, 16);
    a2 += __shfl_xor(a2, 16); a3 += __shfl_xor(a3, 16);
    a0 += __shfl_xor(a0, 32); a1 += __shfl_xor(a1, 32);
    a2 += __shfl_xor(a2, 32); a3 += __shfl_xor(a3, 32);
    if (grp == 0) *(float4*)(G + (size_t)w * 64 + q * 4) = make_float4(a0, a1, a2, a3);
}

// ---------------- h3 = G2@W3 + b3 -> fp32 (64 -> 64, no relu) ----------------
__global__ void k_mm3(const float* __restrict__ G, const float* __restrict__ W,
                      const float* __restrict__ b, float* __restrict__ H, int n) {
    int t = blockIdx.x * TPB + threadIdx.x;
    if (t >= n * 64) return;
    int i = t >> 6, f = t & 63;
    const float* gr = G + (size_t)i * 64;
    float s = b[f];
#pragma unroll
    for (int k = 0; k < 64; k++) s += gr[k] * W[k * 64 + f];
    H[t] = s;
}

// ---------------- pool (max & mean per graph) + classifier + softmax ----------------
__global__ void k_pool(const float* __restrict__ H, const float* __restrict__ Wc,
                       const float* __restrict__ bc, float* __restrict__ out,
                       int n, int g_total) {
    int g = blockIdx.x;
    int f = threadIdx.x & 63;
    int c = threadIdx.x >> 6;  // 0..3 chunks
    long long start = ((long long)g * n + g_total - 1) / g_total;
    long long end = ((long long)(g + 1) * n + g_total - 1) / g_total;
    float mx = -INFINITY, sm = 0.0f;
    for (long long i = start + c; i < end; i += 4) {
        float v = H[(i << 6) | f];
        mx = fmaxf(mx, v);
        sm += v;
    }
    __shared__ float smax[4][64], ssum[4][64], slog[2];
    smax[c][f] = mx; ssum[c][f] = sm;
    __syncthreads();
    if (c == 0) {
        mx = fmaxf(fmaxf(smax[0][f], smax[1][f]), fmaxf(smax[2][f], smax[3][f]));
        sm = ssum[0][f] + ssum[1][f] + ssum[2][f] + ssum[3][f];
        long long cnt = end - start;
        smax[0][f] = mx;
        ssum[0][f] = sm / (float)(cnt > 0 ? cnt : 1);
    }
    __syncthreads();
    if (threadIdx.x < 2) {
        int cls = threadIdx.x;
        float l = bc[cls];
        for (int k = 0; k < 64; k++)
            l += smax[0][k] * Wc[k * 2 + cls] + ssum[0][k] * Wc[(64 + k) * 2 + cls];
        slog[cls] = l;
    }
    __syncthreads();
    if (threadIdx.x == 0) {
        float m = fmaxf(slog[0], slog[1]);
        float e0 = expf(slog[0] - m), e1 = expf(slog[1] - m);
        float inv = 1.0f / (e0 + e1);
        out[g * 2 + 0] = e0 * inv;
        out[g * 2 + 1] = e1 * inv;
    }
}

extern "C" void kernel_launch(void* const* d_in, const int* in_sizes, int n_in,
                              void* d_out, int out_size, void* d_ws, size_t ws_size,
                              hipStream_t stream) {
    const float* x  = (const float*)d_in[0];
    const float* W1 = (const float*)d_in[1];
    const float* b1 = (const float*)d_in[2];
    const float* W2 = (const float*)d_in[3];
    const float* b2 = (const float*)d_in[4];
    const float* W3 = (const float*)d_in[5];
    const float* b3 = (const float*)d_in[6];
    const float* Wc = (const float*)d_in[7];
    const float* bc = (const float*)d_in[8];
    const int*   ei = (const int*)d_in[9];

    const int N = in_sizes[0] / 3;
    const int E = in_sizes[9] / 2;
    const int G = out_size / 2;
    const int* src = ei;
    const int* dst = ei + E;

    char* ws = (char*)d_ws;
    size_t off_b = 0;
    auto alloc = [&](size_t bytes) {
        size_t o = off_b;
        off_b = (off_b + bytes + 255) & ~(size_t)255;
        return (void*)(ws + o);
    };
    float* dinv      = (float*)alloc((size_t)N * 4);
    int*   off       = (int*)alloc((size_t)(N + 1) * 4);
    int*   bucketCnt = (int*)alloc((NB_MAX + 1) * 4);
    int*   bucketOff = (int*)alloc((NB_MAX + 1) * 4);
    int*   bucketCur = (int*)alloc((NB_MAX + 1) * 4);
    int*   csr       = (int*)alloc((size_t)E * 4);
    size_t bufA_sz   = (size_t)N * 64 * 4;
    if ((size_t)E * 8 > bufA_sz) bufA_sz = (size_t)E * 8;
    float* bufA      = (float*)alloc(bufA_sz);          // pairs -> Xa -> G1 -> G2
    float* bufB      = (float*)alloc((size_t)N * 64 * 4);  // T1 -> T2 -> H

    uint2* pairs = (uint2*)bufA;
    float* Xa = bufA;
    unsigned short* T1 = (unsigned short*)bufB;
    float* G1 = bufA;
    unsigned short* T2 = (unsigned short*)bufB;
    float* G2 = bufA;
    float* H  = bufB;

    auto cdiv = [](long long a, long long b) { return (int)((a + b - 1) / b); };
    const int nb = cdiv(N, BKT_NODES);  // coarse buckets (<= NB_MAX)

    // ---- CSR build: coarse hist -> scan -> bin pairs -> per-bucket fine sort ----
    k_zero_i<<<cdiv(nb, TPB), TPB, 0, stream>>>(bucketCnt, nb);
    k_hist_coarse<<<1024, TPB, 0, stream>>>(dst, bucketCnt, E, nb);
    k_scan_buckets<<<1, 256, 0, stream>>>(bucketCnt, bucketOff, bucketCur, off, nb, E, N);
    k_bin_pairs<<<cdiv(E, BIN_CHUNK), TPB, 0, stream>>>(src, dst, bucketCur, pairs, E, nb);
    k_bucket_csr<<<nb, BKT_NODES, 0, stream>>>(pairs, bucketOff, off, dinv, csr, N);

    // ---- layer 1: Xa = S*x (F=3); h1 = relu(Xa@W1+b1) bf16 ----
    k_gather3<<<cdiv(N, TPB), TPB, 0, stream>>>(off, csr, dinv, x, Xa, N);
    k_mm1<<<cdiv((long long)N * 32, TPB), TPB, 0, stream>>>(Xa, W1, b1, T1, N);

    // ---- layer 2: G1 = S*h1 (F=32 bf16); h2 = relu(G1@W2+b2) bf16 ----
    k_gather32b<<<cdiv((long long)N * 64, TPB), TPB, 0, stream>>>(off, csr, dinv, T1, G1, N);
    k_mm2<<<cdiv((long long)N * 64, TPB), TPB, 0, stream>>>(G1, W2, b2, T2, N);

    // ---- layer 3: G2 = S*h2 (F=64 bf16); h3 = G2@W3+b3 fp32 ----
    k_gather64b<<<cdiv((long long)N * 64, TPB), TPB, 0, stream>>>(off, csr, dinv, T2, G2, N);
    k_mm3<<<cdiv((long long)N * 64, TPB), TPB, 0, stream>>>(G2, W3, b3, H, N);

    // ---- pool + classify + softmax ----
    k_pool<<<G, TPB, 0, stream>>>(H, Wc, bc, (float*)d_out, N, G);
}

// Round 5
// 395.440 us; speedup vs baseline: 5.4682x; 1.3598x over previous
//
#include <hip/hip_runtime.h>
#include <math.h>

#define TPB 256
#define NB_MAX 512      // coarse buckets of 256 nodes -> supports N <= 131072
#define BKT_SHIFT 8
#define BKT_NODES 256
#define BIN_CHUNK 8192

__device__ inline float bfLO(unsigned u) { return __uint_as_float(u << 16); }
__device__ inline float bfHI(unsigned u) { return __uint_as_float(u & 0xffff0000u); }
__device__ inline unsigned short f2bf(float f) {
    unsigned int x = __float_as_uint(f);
    return (unsigned short)((x + 0x7fffu + ((x >> 16) & 1u)) >> 16);  // RNE
}

// ---------------- pass A: coarse bucket histogram (LDS) ----------------
__global__ void k_hist_coarse(const int* __restrict__ dst, int* __restrict__ bucketCnt,
                              int e, int nb) {
    __shared__ int h[NB_MAX];
    for (int i = threadIdx.x; i < nb; i += TPB) h[i] = 0;
    __syncthreads();
    for (long long i = (long long)blockIdx.x * TPB + threadIdx.x; i < e;
         i += (long long)gridDim.x * TPB)
        atomicAdd(&h[dst[(int)i] >> BKT_SHIFT], 1);
    __syncthreads();
    for (int i = threadIdx.x; i < nb; i += TPB)
        if (h[i]) atomicAdd(&bucketCnt[i], h[i]);
}

// ---------------- parallel bucket scan (1 block, 512 threads) ----------------
__global__ void k_scanb(const int* __restrict__ cnt, int* __restrict__ boff,
                        int* __restrict__ bcur, int* __restrict__ off_nodes,
                        int nb, int e, int n) {
    __shared__ int lds[NB_MAX];
    int t = threadIdx.x;
    int v = (t < nb) ? cnt[t] : 0;
    lds[t] = v;
    __syncthreads();
    for (int d = 1; d < NB_MAX; d <<= 1) {
        int x = (t >= d) ? lds[t - d] : 0;
        __syncthreads();
        lds[t] += x;
        __syncthreads();
    }
    int excl = lds[t] - v;
    if (t < nb) { boff[t] = excl; bcur[t] = excl; }
    if (t == nb - 1) boff[nb] = lds[t];
    if (t == 0) off_nodes[n] = e;
}

// ---------------- pass B: bin packed (src | local_dst<<24) by coarse bucket ----------------
__global__ void k_bin_pairs(const int* __restrict__ src, const int* __restrict__ dst,
                            int* __restrict__ bucketCur, unsigned* __restrict__ pairs,
                            int e, int nb) {
    __shared__ int h[NB_MAX];
    __shared__ int base[NB_MAX];
    int e0 = blockIdx.x * BIN_CHUNK;
    int e1 = min(e0 + BIN_CHUNK, e);
    for (int i = threadIdx.x; i < nb; i += TPB) h[i] = 0;
    __syncthreads();
    for (int i = e0 + threadIdx.x; i < e1; i += TPB)
        atomicAdd(&h[dst[i] >> BKT_SHIFT], 1);
    __syncthreads();
    for (int i = threadIdx.x; i < nb; i += TPB) {
        int c = h[i];
        base[i] = c ? atomicAdd(&bucketCur[i], c) : 0;
        h[i] = 0;  // reuse as intra-block cursor
    }
    __syncthreads();
    for (int i = e0 + threadIdx.x; i < e1; i += TPB) {
        int d = dst[i];
        int b = d >> BKT_SHIFT;
        int pos = base[b] + atomicAdd(&h[b], 1);
        pairs[pos] = ((unsigned)(d & (BKT_NODES - 1)) << 24) | (unsigned)src[i];
    }
}

// ---------------- pass C: per-bucket fine CSR + node offsets + dinv ----------------
__global__ void k_bucket_csr(const unsigned* __restrict__ pairs, const int* __restrict__ bucketOff,
                             int* __restrict__ off_nodes, float* __restrict__ dinv,
                             int* __restrict__ csr, int n) {
    __shared__ int hist[BKT_NODES];
    __shared__ int offl[BKT_NODES];
    __shared__ int cur[BKT_NODES];
    int b = blockIdx.x;
    int t = threadIdx.x;  // 256 threads
    int e0 = bucketOff[b], e1 = bucketOff[b + 1];
    int nbase = b << BKT_SHIFT;
    hist[t] = 0;
    __syncthreads();
    for (int e = e0 + t; e < e1; e += BKT_NODES)
        atomicAdd(&hist[pairs[e] >> 24], 1);
    __syncthreads();
    int v = hist[t];
    offl[t] = v;
    __syncthreads();
    for (int d = 1; d < BKT_NODES; d <<= 1) {
        int x = (t >= d) ? offl[t - d] : 0;
        __syncthreads();
        offl[t] += x;
        __syncthreads();
    }
    int excl = offl[t] - v;
    cur[t] = excl;
    int nd = nbase + t;
    if (nd < n) {
        off_nodes[nd] = e0 + excl;
        dinv[nd] = rsqrtf((float)(v + 1));  // +1 self loop
    }
    __syncthreads();
    for (int e = e0 + t; e < e1; e += BKT_NODES) {
        unsigned p = pairs[e];
        int l = (int)(p >> 24);
        int pos = e0 + atomicAdd(&cur[l], 1);
        csr[pos] = (int)(p & 0xffffffu);
    }
}

// ---------------- x' = dinv * x ----------------
__global__ void k_scale3(const float* __restrict__ x, const float* __restrict__ dinv,
                         float* __restrict__ xp, int n3) {
    int t = blockIdx.x * TPB + threadIdx.x;
    if (t >= n3) return;
    xp[t] = x[t] * dinv[t / 3];
}

// ---------------- fused gather(F=3) + mm1 + relu -> T1' = dinv*h1 (bf16) ----------------
__global__ void k_g3mm1(const int* __restrict__ off, const int* __restrict__ csr,
                        const float* __restrict__ dinv, const float* __restrict__ xp,
                        const float* __restrict__ W1, const float* __restrict__ b1,
                        unsigned short* __restrict__ T1, int n) {
    __shared__ float w1s[96];
    __shared__ float b1s[32];
    if (threadIdx.x < 96) w1s[threadIdx.x] = W1[threadIdx.x];
    if (threadIdx.x < 32) b1s[threadIdx.x] = b1[threadIdx.x];
    __syncthreads();
    int i = blockIdx.x * TPB + threadIdx.x;
    if (i >= n) return;
    float s0 = xp[i * 3], s1 = xp[i * 3 + 1], s2 = xp[i * 3 + 2];  // self (pre-scaled)
    int e = off[i], e1 = off[i + 1];
    for (; e + 3 < e1; e += 4) {
        int sa = csr[e], sb = csr[e + 1], sc = csr[e + 2], sd = csr[e + 3];
        float a0 = xp[sa * 3], a1 = xp[sa * 3 + 1], a2 = xp[sa * 3 + 2];
        float c0 = xp[sb * 3], c1 = xp[sb * 3 + 1], c2 = xp[sb * 3 + 2];
        float d0 = xp[sc * 3], d1 = xp[sc * 3 + 1], d2 = xp[sc * 3 + 2];
        float f0 = xp[sd * 3], f1 = xp[sd * 3 + 1], f2 = xp[sd * 3 + 2];
        s0 += a0 + c0 + d0 + f0;
        s1 += a1 + c1 + d1 + f1;
        s2 += a2 + c2 + d2 + f2;
    }
    for (; e < e1; ++e) {
        int s = csr[e];
        s0 += xp[s * 3]; s1 += xp[s * 3 + 1]; s2 += xp[s * 3 + 2];
    }
    float di = dinv[i];
    s0 *= di; s1 *= di; s2 *= di;   // Xa row
    unsigned outw[16];
#pragma unroll
    for (int fp = 0; fp < 16; fp++) {
        float h0 = fmaf(s0, w1s[2 * fp], fmaf(s1, w1s[32 + 2 * fp], fmaf(s2, w1s[64 + 2 * fp], b1s[2 * fp])));
        float h1 = fmaf(s0, w1s[2 * fp + 1], fmaf(s1, w1s[32 + 2 * fp + 1], fmaf(s2, w1s[64 + 2 * fp + 1], b1s[2 * fp + 1])));
        h0 = fmaxf(h0, 0.0f) * di;
        h1 = fmaxf(h1, 0.0f) * di;
        outw[fp] = (unsigned)f2bf(h0) | ((unsigned)f2bf(h1) << 16);
    }
    uint4* o = (uint4*)(T1 + (size_t)i * 32);
    o[0] = make_uint4(outw[0], outw[1], outw[2], outw[3]);
    o[1] = make_uint4(outw[4], outw[5], outw[6], outw[7]);
    o[2] = make_uint4(outw[8], outw[9], outw[10], outw[11]);
    o[3] = make_uint4(outw[12], outw[13], outw[14], outw[15]);
}

#define ACC8(v) do { \
    a0 += bfLO((v).x); a1 += bfHI((v).x); a2 += bfLO((v).y); a3 += bfHI((v).y); \
    a4 += bfLO((v).z); a5 += bfHI((v).z); a6 += bfLO((v).w); a7 += bfHI((v).w); } while (0)

// ---------------- gather F=32 (T pre-scaled bf16): 4 lanes/edge, 16 edges/iter ----------------
__global__ void k_gather32b(const int* __restrict__ off, const int* __restrict__ csr,
                            const float* __restrict__ dinv, const unsigned short* __restrict__ T,
                            float* __restrict__ G, int n) {
    int w = (blockIdx.x * TPB + threadIdx.x) >> 6;
    if (w >= n) return;
    int lane = threadIdx.x & 63;
    int grp = lane >> 2, q = lane & 3;   // feats q*8..q*8+7
    float a0 = 0, a1 = 0, a2 = 0, a3 = 0, a4 = 0, a5 = 0, a6 = 0, a7 = 0;
    if (grp == 0) {
        uint4 v = *(const uint4*)(T + ((size_t)w << 5) + (q << 3));
        ACC8(v);  // self (pre-scaled by dinv[w])
    }
    int e = off[w] + grp, e1 = off[w + 1];
    for (; e + 16 < e1; e += 32) {
        int s0 = csr[e], s1 = csr[e + 16];
        uint4 v0 = *(const uint4*)(T + ((size_t)s0 << 5) + (q << 3));
        uint4 v1 = *(const uint4*)(T + ((size_t)s1 << 5) + (q << 3));
        ACC8(v0); ACC8(v1);
    }
    if (e < e1) {
        int s = csr[e];
        uint4 v = *(const uint4*)(T + ((size_t)s << 5) + (q << 3));
        ACC8(v);
    }
#pragma unroll
    for (int m = 4; m < 64; m <<= 1) {
        a0 += __shfl_xor(a0, m); a1 += __shfl_xor(a1, m);
        a2 += __shfl_xor(a2, m); a3 += __shfl_xor(a3, m);
        a4 += __shfl_xor(a4, m); a5 += __shfl_xor(a5, m);
        a6 += __shfl_xor(a6, m); a7 += __shfl_xor(a7, m);
    }
    if (grp == 0) {
        float di = dinv[w];
        float* g = G + ((size_t)w << 5) + (q << 3);
        *(float4*)g = make_float4(a0 * di, a1 * di, a2 * di, a3 * di);
        *(float4*)(g + 4) = make_float4(a4 * di, a5 * di, a6 * di, a7 * di);
    }
}

// ---------------- h2 = relu(G1@W2 + b2) * dinv -> bf16 (32 -> 64) ----------------
__global__ void k_mm2(const float* __restrict__ G, const float* __restrict__ W,
                      const float* __restrict__ b, const float* __restrict__ dinv,
                      unsigned short* __restrict__ T, int n) {
    int t = blockIdx.x * TPB + threadIdx.x;
    if (t >= n * 64) return;
    int i = t >> 6, f = t & 63;
    const float* gr = G + (size_t)i * 32;
    float s = b[f];
#pragma unroll
    for (int k = 0; k < 32; k++) s += gr[k] * W[k * 64 + f];
    T[t] = f2bf(fmaxf(s, 0.0f) * dinv[i]);
}

// ---------------- gather F=64 (T pre-scaled bf16): 8 lanes/edge, 8 edges/iter ----------------
__global__ void k_gather64b(const int* __restrict__ off, const int* __restrict__ csr,
                            const float* __restrict__ dinv, const unsigned short* __restrict__ T,
                            float* __restrict__ G, int n) {
    int w = (blockIdx.x * TPB + threadIdx.x) >> 6;
    if (w >= n) return;
    int lane = threadIdx.x & 63;
    int grp = lane >> 3, q = lane & 7;   // feats q*8..q*8+7
    float a0 = 0, a1 = 0, a2 = 0, a3 = 0, a4 = 0, a5 = 0, a6 = 0, a7 = 0;
    if (grp == 0) {
        uint4 v = *(const uint4*)(T + ((size_t)w << 6) + (q << 3));
        ACC8(v);  // self
    }
    int e = off[w] + grp, e1 = off[w + 1];
    for (; e + 8 < e1; e += 16) {
        int s0 = csr[e], s1 = csr[e + 8];
        uint4 v0 = *(const uint4*)(T + ((size_t)s0 << 6) + (q << 3));
        uint4 v1 = *(const uint4*)(T + ((size_t)s1 << 6) + (q << 3));
        ACC8(v0); ACC8(v1);
    }
    if (e < e1) {
        int s = csr[e];
        uint4 v = *(const uint4*)(T + ((size_t)s << 6) + (q << 3));
        ACC8(v);
    }
#pragma unroll
    for (int m = 8; m < 64; m <<= 1) {
        a0 += __shfl_xor(a0, m); a1 += __shfl_xor(a1, m);
        a2 += __shfl_xor(a2, m); a3 += __shfl_xor(a3, m);
        a4 += __shfl_xor(a4, m); a5 += __shfl_xor(a5, m);
        a6 += __shfl_xor(a6, m); a7 += __shfl_xor(a7, m);
    }
    if (grp == 0) {
        float di = dinv[w];
        float* g = G + ((size_t)w << 6) + (q << 3);
        *(float4*)g = make_float4(a0 * di, a1 * di, a2 * di, a3 * di);
        *(float4*)(g + 4) = make_float4(a4 * di, a5 * di, a6 * di, a7 * di);
    }
}

// ---------------- h3 = G2@W3 + b3 -> fp32 (64 -> 64, no relu) ----------------
__global__ void k_mm3(const float* __restrict__ G, const float* __restrict__ W,
                      const float* __restrict__ b, float* __restrict__ H, int n) {
    int t = blockIdx.x * TPB + threadIdx.x;
    if (t >= n * 64) return;
    int i = t >> 6, f = t & 63;
    const float* gr = G + (size_t)i * 64;
    float s = b[f];
#pragma unroll
    for (int k = 0; k < 64; k++) s += gr[k] * W[k * 64 + f];
    H[t] = s;
}

// ---------------- pool (max & mean per graph) + classifier + softmax ----------------
__global__ void k_pool(const float* __restrict__ H, const float* __restrict__ Wc,
                       const float* __restrict__ bc, float* __restrict__ out,
                       int n, int g_total) {
    int g = blockIdx.x;
    int f = threadIdx.x & 63;
    int c = threadIdx.x >> 6;  // 0..3 chunks
    long long start = ((long long)g * n + g_total - 1) / g_total;
    long long end = ((long long)(g + 1) * n + g_total - 1) / g_total;
    float mx = -INFINITY, sm = 0.0f;
    for (long long i = start + c; i < end; i += 4) {
        float v = H[(i << 6) | f];
        mx = fmaxf(mx, v);
        sm += v;
    }
    __shared__ float smax[4][64], ssum[4][64], slog[2];
    smax[c][f] = mx; ssum[c][f] = sm;
    __syncthreads();
    if (c == 0) {
        mx = fmaxf(fmaxf(smax[0][f], smax[1][f]), fmaxf(smax[2][f], smax[3][f]));
        sm = ssum[0][f] + ssum[1][f] + ssum[2][f] + ssum[3][f];
        long long cnt = end - start;
        smax[0][f] = mx;
        ssum[0][f] = sm / (float)(cnt > 0 ? cnt : 1);
    }
    __syncthreads();
    if (threadIdx.x < 2) {
        int cls = threadIdx.x;
        float l = bc[cls];
        for (int k = 0; k < 64; k++)
            l += smax[0][k] * Wc[k * 2 + cls] + ssum[0][k] * Wc[(64 + k) * 2 + cls];
        slog[cls] = l;
    }
    __syncthreads();
    if (threadIdx.x == 0) {
        float m = fmaxf(slog[0], slog[1]);
        float e0 = expf(slog[0] - m), e1 = expf(slog[1] - m);
        float inv = 1.0f / (e0 + e1);
        out[g * 2 + 0] = e0 * inv;
        out[g * 2 + 1] = e1 * inv;
    }
}

extern "C" void kernel_launch(void* const* d_in, const int* in_sizes, int n_in,
                              void* d_out, int out_size, void* d_ws, size_t ws_size,
                              hipStream_t stream) {
    const float* x  = (const float*)d_in[0];
    const float* W1 = (const float*)d_in[1];
    const float* b1 = (const float*)d_in[2];
    const float* W2 = (const float*)d_in[3];
    const float* b2 = (const float*)d_in[4];
    const float* W3 = (const float*)d_in[5];
    const float* b3 = (const float*)d_in[6];
    const float* Wc = (const float*)d_in[7];
    const float* bc = (const float*)d_in[8];
    const int*   ei = (const int*)d_in[9];

    const int N = in_sizes[0] / 3;
    const int E = in_sizes[9] / 2;
    const int G = out_size / 2;
    const int* src = ei;
    const int* dst = ei + E;

    char* ws = (char*)d_ws;
    size_t off_b = 0;
    auto alloc = [&](size_t bytes) {
        size_t o = off_b;
        off_b = (off_b + bytes + 255) & ~(size_t)255;
        return (void*)(ws + o);
    };
    float* dinv      = (float*)alloc((size_t)N * 4);
    int*   off       = (int*)alloc((size_t)(N + 1) * 4);
    int*   bucketCnt = (int*)alloc((NB_MAX + 1) * 4);
    int*   bucketOff = (int*)alloc((NB_MAX + 1) * 4);
    int*   bucketCur = (int*)alloc((NB_MAX + 1) * 4);
    int*   csr       = (int*)alloc((size_t)E * 4);
    float* xp        = (float*)alloc((size_t)N * 3 * 4);
    size_t bufA_sz   = (size_t)N * 64 * 4;
    if ((size_t)E * 4 > bufA_sz) bufA_sz = (size_t)E * 4;
    float* bufA      = (float*)alloc(bufA_sz);              // pairs -> G1 -> G2
    float* bufB      = (float*)alloc((size_t)N * 64 * 4);   // T1' -> T2' -> H

    unsigned* pairs = (unsigned*)bufA;
    float* G1 = bufA;
    float* G2 = bufA;
    unsigned short* T1 = (unsigned short*)bufB;
    unsigned short* T2 = (unsigned short*)bufB;
    float* H  = bufB;

    auto cdiv = [](long long a, long long b) { return (int)((a + b - 1) / b); };
    const int nb = cdiv(N, BKT_NODES);  // coarse buckets (<= NB_MAX)

    // ---- CSR build ----
    hipMemsetAsync(bucketCnt, 0, (size_t)nb * 4, stream);
    k_hist_coarse<<<1024, TPB, 0, stream>>>(dst, bucketCnt, E, nb);
    k_scanb<<<1, NB_MAX, 0, stream>>>(bucketCnt, bucketOff, bucketCur, off, nb, E, N);
    k_bin_pairs<<<cdiv(E, BIN_CHUNK), TPB, 0, stream>>>(src, dst, bucketCur, pairs, E, nb);
    k_bucket_csr<<<nb, BKT_NODES, 0, stream>>>(pairs, bucketOff, off, dinv, csr, N);

    // ---- layer 1 (fused): x' = dinv*x; T1' = dinv*relu(S'x'@W1+b1) ----
    k_scale3<<<cdiv((long long)N * 3, TPB), TPB, 0, stream>>>(x, dinv, xp, N * 3);
    k_g3mm1<<<cdiv(N, TPB), TPB, 0, stream>>>(off, csr, dinv, xp, W1, b1, T1, N);

    // ---- layer 2: G1 = dinv * (sum T1') ; T2' = dinv*relu(G1@W2+b2) ----
    k_gather32b<<<cdiv((long long)N * 64, TPB), TPB, 0, stream>>>(off, csr, dinv, T1, G1, N);
    k_mm2<<<cdiv((long long)N * 64, TPB), TPB, 0, stream>>>(G1, W2, b2, dinv, T2, N);

    // ---- layer 3: G2 = dinv * (sum T2') ; H = G2@W3+b3 ----
    k_gather64b<<<cdiv((long long)N * 64, TPB), TPB, 0, stream>>>(off, csr, dinv, T2, G2, N);
    k_mm3<<<cdiv((long long)N * 64, TPB), TPB, 0, stream>>>(G2, W3, b3, H, N);

    // ---- pool + classify + softmax ----
    k_pool<<<G, TPB, 0, stream>>>(H, Wc, bc, (float*)d_out, N, G);
}

// Round 6
// 323.636 us; speedup vs baseline: 6.6814x; 1.2219x over previous
//
#include <hip/hip_runtime.h>
#include <math.h>

#define TPB 256
#define NB_MAX 512      // coarse buckets of 256 nodes -> supports N <= 131072
#define BKT_SHIFT 8
#define BKT_NODES 256
#define BIN_CHUNK 8192

__device__ inline float bfLO(unsigned u) { return __uint_as_float(u << 16); }
__device__ inline float bfHI(unsigned u) { return __uint_as_float(u & 0xffff0000u); }
__device__ inline unsigned short f2bf(float f) {
    unsigned int x = __float_as_uint(f);
    return (unsigned short)((x + 0x7fffu + ((x >> 16) & 1u)) >> 16);  // RNE
}

// ---------------- pass A: coarse bucket histogram (LDS) ----------------
__global__ void k_hist_coarse(const int* __restrict__ dst, int* __restrict__ bucketCnt,
                              int e, int nb) {
    __shared__ int h[NB_MAX];
    for (int i = threadIdx.x; i < nb; i += TPB) h[i] = 0;
    __syncthreads();
    for (long long i = (long long)blockIdx.x * TPB + threadIdx.x; i < e;
         i += (long long)gridDim.x * TPB)
        atomicAdd(&h[dst[(int)i] >> BKT_SHIFT], 1);
    __syncthreads();
    for (int i = threadIdx.x; i < nb; i += TPB)
        if (h[i]) atomicAdd(&bucketCnt[i], h[i]);
}

// ---------------- parallel bucket scan (1 block) ----------------
__global__ void k_scanb(const int* __restrict__ cnt, int* __restrict__ boff,
                        int* __restrict__ bcur, int* __restrict__ off_nodes,
                        int nb, int e, int n) {
    __shared__ int lds[NB_MAX];
    int t = threadIdx.x;
    int v = (t < nb) ? cnt[t] : 0;
    lds[t] = v;
    __syncthreads();
    for (int d = 1; d < NB_MAX; d <<= 1) {
        int x = (t >= d) ? lds[t - d] : 0;
        __syncthreads();
        lds[t] += x;
        __syncthreads();
    }
    int excl = lds[t] - v;
    if (t < nb) { boff[t] = excl; bcur[t] = excl; }
    if (t == nb - 1) boff[nb] = lds[t];
    if (t == 0) off_nodes[n] = e;
}

// ---------------- pass B: bin packed (src | local_dst<<24) by coarse bucket ----------------
__global__ void k_bin_pairs(const int* __restrict__ src, const int* __restrict__ dst,
                            int* __restrict__ bucketCur, unsigned* __restrict__ pairs,
                            int e, int nb) {
    __shared__ int h[NB_MAX];
    __shared__ int base[NB_MAX];
    int e0 = blockIdx.x * BIN_CHUNK;
    int e1 = min(e0 + BIN_CHUNK, e);
    for (int i = threadIdx.x; i < nb; i += TPB) h[i] = 0;
    __syncthreads();
    for (int i = e0 + threadIdx.x; i < e1; i += TPB)
        atomicAdd(&h[dst[i] >> BKT_SHIFT], 1);
    __syncthreads();
    for (int i = threadIdx.x; i < nb; i += TPB) {
        int c = h[i];
        base[i] = c ? atomicAdd(&bucketCur[i], c) : 0;
        h[i] = 0;  // reuse as intra-block cursor
    }
    __syncthreads();
    for (int i = e0 + threadIdx.x; i < e1; i += TPB) {
        int d = dst[i];
        int b = d >> BKT_SHIFT;
        int pos = base[b] + atomicAdd(&h[b], 1);
        pairs[pos] = ((unsigned)(d & (BKT_NODES - 1)) << 24) | (unsigned)src[i];
    }
}

// ---------------- pass C: per-bucket fine CSR + node offsets + dinv ----------------
__global__ void k_bucket_csr(const unsigned* __restrict__ pairs, const int* __restrict__ bucketOff,
                             int* __restrict__ off_nodes, float* __restrict__ dinv,
                             int* __restrict__ csr, int n) {
    __shared__ int hist[BKT_NODES];
    __shared__ int offl[BKT_NODES];
    __shared__ int cur[BKT_NODES];
    int b = blockIdx.x;
    int t = threadIdx.x;  // 256 threads
    int e0 = bucketOff[b], e1 = bucketOff[b + 1];
    int nbase = b << BKT_SHIFT;
    hist[t] = 0;
    __syncthreads();
    for (int e = e0 + t; e < e1; e += BKT_NODES)
        atomicAdd(&hist[pairs[e] >> 24], 1);
    __syncthreads();
    int v = hist[t];
    offl[t] = v;
    __syncthreads();
    for (int d = 1; d < BKT_NODES; d <<= 1) {
        int x = (t >= d) ? offl[t - d] : 0;
        __syncthreads();
        offl[t] += x;
        __syncthreads();
    }
    int excl = offl[t] - v;
    cur[t] = excl;
    int nd = nbase + t;
    if (nd < n) {
        off_nodes[nd] = e0 + excl;
        dinv[nd] = rsqrtf((float)(v + 1));  // +1 self loop
    }
    __syncthreads();
    for (int e = e0 + t; e < e1; e += BKT_NODES) {
        unsigned p = pairs[e];
        int l = (int)(p >> 24);
        int pos = e0 + atomicAdd(&cur[l], 1);
        csr[pos] = (int)(p & 0xffffffu);
    }
}

// ---------------- x' = dinv * x ----------------
__global__ void k_scale3(const float* __restrict__ x, const float* __restrict__ dinv,
                         float* __restrict__ xp, int n3) {
    int t = blockIdx.x * TPB + threadIdx.x;
    if (t >= n3) return;
    xp[t] = x[t] * dinv[t / 3];
}

// ---------------- fused gather(F=3) + mm1 + relu -> T1' = dinv*h1 (bf16) ----------------
__global__ void k_g3mm1(const int* __restrict__ off, const int* __restrict__ csr,
                        const float* __restrict__ dinv, const float* __restrict__ xp,
                        const float* __restrict__ W1, const float* __restrict__ b1,
                        unsigned short* __restrict__ T1, int n) {
    __shared__ float w1s[96];
    __shared__ float b1s[32];
    if (threadIdx.x < 96) w1s[threadIdx.x] = W1[threadIdx.x];
    if (threadIdx.x < 32) b1s[threadIdx.x] = b1[threadIdx.x];
    __syncthreads();
    int i = blockIdx.x * TPB + threadIdx.x;
    if (i >= n) return;
    float s0 = xp[i * 3], s1 = xp[i * 3 + 1], s2 = xp[i * 3 + 2];  // self (pre-scaled)
    int e = off[i], e1 = off[i + 1];
    for (; e + 3 < e1; e += 4) {
        int sa = csr[e], sb = csr[e + 1], sc = csr[e + 2], sd = csr[e + 3];
        float a0 = xp[sa * 3], a1 = xp[sa * 3 + 1], a2 = xp[sa * 3 + 2];
        float c0 = xp[sb * 3], c1 = xp[sb * 3 + 1], c2 = xp[sb * 3 + 2];
        float d0 = xp[sc * 3], d1 = xp[sc * 3 + 1], d2 = xp[sc * 3 + 2];
        float f0 = xp[sd * 3], f1 = xp[sd * 3 + 1], f2 = xp[sd * 3 + 2];
        s0 += a0 + c0 + d0 + f0;
        s1 += a1 + c1 + d1 + f1;
        s2 += a2 + c2 + d2 + f2;
    }
    for (; e < e1; ++e) {
        int s = csr[e];
        s0 += xp[s * 3]; s1 += xp[s * 3 + 1]; s2 += xp[s * 3 + 2];
    }
    float di = dinv[i];
    s0 *= di; s1 *= di; s2 *= di;   // Xa row
    unsigned outw[16];
#pragma unroll
    for (int fp = 0; fp < 16; fp++) {
        float h0 = fmaf(s0, w1s[2 * fp], fmaf(s1, w1s[32 + 2 * fp], fmaf(s2, w1s[64 + 2 * fp], b1s[2 * fp])));
        float h1 = fmaf(s0, w1s[2 * fp + 1], fmaf(s1, w1s[32 + 2 * fp + 1], fmaf(s2, w1s[64 + 2 * fp + 1], b1s[2 * fp + 1])));
        h0 = fmaxf(h0, 0.0f) * di;
        h1 = fmaxf(h1, 0.0f) * di;
        outw[fp] = (unsigned)f2bf(h0) | ((unsigned)f2bf(h1) << 16);
    }
    uint4* o = (uint4*)(T1 + (size_t)i * 32);
    o[0] = make_uint4(outw[0], outw[1], outw[2], outw[3]);
    o[1] = make_uint4(outw[4], outw[5], outw[6], outw[7]);
    o[2] = make_uint4(outw[8], outw[9], outw[10], outw[11]);
    o[3] = make_uint4(outw[12], outw[13], outw[14], outw[15]);
}

#define ACC8(v) do { \
    a0 += bfLO((v).x); a1 += bfHI((v).x); a2 += bfLO((v).y); a3 += bfHI((v).y); \
    a4 += bfLO((v).z); a5 += bfHI((v).z); a6 += bfLO((v).w); a7 += bfHI((v).w); } while (0)

// ---------------- gather F=32 (T pre-scaled bf16): 4 lanes/edge, 16 edges/iter ----------------
__global__ void k_gather32b(const int* __restrict__ off, const int* __restrict__ csr,
                            const float* __restrict__ dinv, const unsigned short* __restrict__ T,
                            float* __restrict__ G, int n) {
    int w = (blockIdx.x * TPB + threadIdx.x) >> 6;
    if (w >= n) return;
    int lane = threadIdx.x & 63;
    int grp = lane >> 2, q = lane & 3;   // feats q*8..q*8+7
    float a0 = 0, a1 = 0, a2 = 0, a3 = 0, a4 = 0, a5 = 0, a6 = 0, a7 = 0;
    if (grp == 0) {
        uint4 v = *(const uint4*)(T + ((size_t)w << 5) + (q << 3));
        ACC8(v);  // self (pre-scaled by dinv[w])
    }
    int e = off[w] + grp, e1 = off[w + 1];
    for (; e + 16 < e1; e += 32) {
        int s0 = csr[e], s1 = csr[e + 16];
        uint4 v0 = *(const uint4*)(T + ((size_t)s0 << 5) + (q << 3));
        uint4 v1 = *(const uint4*)(T + ((size_t)s1 << 5) + (q << 3));
        ACC8(v0); ACC8(v1);
    }
    if (e < e1) {
        int s = csr[e];
        uint4 v = *(const uint4*)(T + ((size_t)s << 5) + (q << 3));
        ACC8(v);
    }
#pragma unroll
    for (int m = 4; m < 64; m <<= 1) {
        a0 += __shfl_xor(a0, m); a1 += __shfl_xor(a1, m);
        a2 += __shfl_xor(a2, m); a3 += __shfl_xor(a3, m);
        a4 += __shfl_xor(a4, m); a5 += __shfl_xor(a5, m);
        a6 += __shfl_xor(a6, m); a7 += __shfl_xor(a7, m);
    }
    if (grp == 0) {
        float di = dinv[w];
        float* g = G + ((size_t)w << 5) + (q << 3);
        *(float4*)g = make_float4(a0 * di, a1 * di, a2 * di, a3 * di);
        *(float4*)(g + 4) = make_float4(a4 * di, a5 * di, a6 * di, a7 * di);
    }
}

// ---------------- mm2: one node per lane; T2' = dinv*relu(G1@W2+b2) bf16 ----------------
__global__ void k_mm2(const float* __restrict__ G, const float* __restrict__ W,
                      const float* __restrict__ b, const float* __restrict__ dinv,
                      unsigned short* __restrict__ T, int n) {
    int i = blockIdx.x * TPB + threadIdx.x;
    if (i >= n) return;
    float gr[32];
    const float4* g4 = (const float4*)(G + (size_t)i * 32);
#pragma unroll
    for (int c = 0; c < 8; c++) {
        float4 v = g4[c];
        gr[4 * c] = v.x; gr[4 * c + 1] = v.y; gr[4 * c + 2] = v.z; gr[4 * c + 3] = v.w;
    }
    float di = dinv[i];
    uint2* o = (uint2*)(T + (size_t)i * 64);
    for (int fc = 0; fc < 16; fc++) {  // output chunks of 4
        const float* bb = b + 4 * fc;
        float a0 = bb[0], a1 = bb[1], a2 = bb[2], a3 = bb[3];
#pragma unroll
        for (int k = 0; k < 32; k++) {
            const float* wr = W + k * 64 + 4 * fc;  // wave-uniform address
            float g = gr[k];
            a0 = fmaf(g, wr[0], a0);
            a1 = fmaf(g, wr[1], a1);
            a2 = fmaf(g, wr[2], a2);
            a3 = fmaf(g, wr[3], a3);
        }
        a0 = fmaxf(a0, 0.0f) * di; a1 = fmaxf(a1, 0.0f) * di;
        a2 = fmaxf(a2, 0.0f) * di; a3 = fmaxf(a3, 0.0f) * di;
        o[fc] = make_uint2((unsigned)f2bf(a0) | ((unsigned)f2bf(a1) << 16),
                           (unsigned)f2bf(a2) | ((unsigned)f2bf(a3) << 16));
    }
}

// ---------------- gather F=64 (T pre-scaled bf16): 8 lanes/edge, 8 edges/iter ----------------
__global__ void k_gather64b(const int* __restrict__ off, const int* __restrict__ csr,
                            const float* __restrict__ dinv, const unsigned short* __restrict__ T,
                            float* __restrict__ G, int n) {
    int w = (blockIdx.x * TPB + threadIdx.x) >> 6;
    if (w >= n) return;
    int lane = threadIdx.x & 63;
    int grp = lane >> 3, q = lane & 7;   // feats q*8..q*8+7
    float a0 = 0, a1 = 0, a2 = 0, a3 = 0, a4 = 0, a5 = 0, a6 = 0, a7 = 0;
    if (grp == 0) {
        uint4 v = *(const uint4*)(T + ((size_t)w << 6) + (q << 3));
        ACC8(v);  // self
    }
    int e = off[w] + grp, e1 = off[w + 1];
    for (; e + 8 < e1; e += 16) {
        int s0 = csr[e], s1 = csr[e + 8];
        uint4 v0 = *(const uint4*)(T + ((size_t)s0 << 6) + (q << 3));
        uint4 v1 = *(const uint4*)(T + ((size_t)s1 << 6) + (q << 3));
        ACC8(v0); ACC8(v1);
    }
    if (e < e1) {
        int s = csr[e];
        uint4 v = *(const uint4*)(T + ((size_t)s << 6) + (q << 3));
        ACC8(v);
    }
#pragma unroll
    for (int m = 8; m < 64; m <<= 1) {
        a0 += __shfl_xor(a0, m); a1 += __shfl_xor(a1, m);
        a2 += __shfl_xor(a2, m); a3 += __shfl_xor(a3, m);
        a4 += __shfl_xor(a4, m); a5 += __shfl_xor(a5, m);
        a6 += __shfl_xor(a6, m); a7 += __shfl_xor(a7, m);
    }
    if (grp == 0) {
        float di = dinv[w];
        float* g = G + ((size_t)w << 6) + (q << 3);
        *(float4*)g = make_float4(a0 * di, a1 * di, a2 * di, a3 * di);
        *(float4*)(g + 4) = make_float4(a4 * di, a5 * di, a6 * di, a7 * di);
    }
}

// ---------------- mm3: one node per lane; H = G2@W3 + b3 (fp32, no relu) ----------------
__global__ void k_mm3(const float* __restrict__ G, const float* __restrict__ W,
                      const float* __restrict__ b, float* __restrict__ H, int n) {
    int i = blockIdx.x * TPB + threadIdx.x;
    if (i >= n) return;
    float gr[64];
    const float4* g4 = (const float4*)(G + (size_t)i * 64);
#pragma unroll
    for (int c = 0; c < 16; c++) {
        float4 v = g4[c];
        gr[4 * c] = v.x; gr[4 * c + 1] = v.y; gr[4 * c + 2] = v.z; gr[4 * c + 3] = v.w;
    }
    float4* h4 = (float4*)(H + (size_t)i * 64);
    for (int fc = 0; fc < 16; fc++) {  // output chunks of 4
        const float* bb = b + 4 * fc;
        float a0 = bb[0], a1 = bb[1], a2 = bb[2], a3 = bb[3];
#pragma unroll
        for (int k = 0; k < 64; k++) {
            const float* wr = W + k * 64 + 4 * fc;  // wave-uniform address
            float g = gr[k];
            a0 = fmaf(g, wr[0], a0);
            a1 = fmaf(g, wr[1], a1);
            a2 = fmaf(g, wr[2], a2);
            a3 = fmaf(g, wr[3], a3);
        }
        h4[fc] = make_float4(a0, a1, a2, a3);
    }
}

// ---------------- pool (max & mean per graph) + classifier + softmax ----------------
__global__ void k_pool(const float* __restrict__ H, const float* __restrict__ Wc,
                       const float* __restrict__ bc, float* __restrict__ out,
                       int n, int g_total) {
    int g = blockIdx.x;
    int f = threadIdx.x & 63;
    int c = threadIdx.x >> 6;  // 0..3 chunks
    long long start = ((long long)g * n + g_total - 1) / g_total;
    long long end = ((long long)(g + 1) * n + g_total - 1) / g_total;
    float mx = -INFINITY, sm = 0.0f;
    for (long long i = start + c; i < end; i += 4) {
        float v = H[(i << 6) | f];
        mx = fmaxf(mx, v);
        sm += v;
    }
    __shared__ float smax[4][64], ssum[4][64], slog[2];
    smax[c][f] = mx; ssum[c][f] = sm;
    __syncthreads();
    if (c == 0) {
        mx = fmaxf(fmaxf(smax[0][f], smax[1][f]), fmaxf(smax[2][f], smax[3][f]));
        sm = ssum[0][f] + ssum[1][f] + ssum[2][f] + ssum[3][f];
        long long cnt = end - start;
        smax[0][f] = mx;
        ssum[0][f] = sm / (float)(cnt > 0 ? cnt : 1);
    }
    __syncthreads();
    if (threadIdx.x < 2) {
        int cls = threadIdx.x;
        float l = bc[cls];
        for (int k = 0; k < 64; k++)
            l += smax[0][k] * Wc[k * 2 + cls] + ssum[0][k] * Wc[(64 + k) * 2 + cls];
        slog[cls] = l;
    }
    __syncthreads();
    if (threadIdx.x == 0) {
        float m = fmaxf(slog[0], slog[1]);
        float e0 = expf(slog[0] - m), e1 = expf(slog[1] - m);
        float inv = 1.0f / (e0 + e1);
        out[g * 2 + 0] = e0 * inv;
        out[g * 2 + 1] = e1 * inv;
    }
}

extern "C" void kernel_launch(void* const* d_in, const int* in_sizes, int n_in,
                              void* d_out, int out_size, void* d_ws, size_t ws_size,
                              hipStream_t stream) {
    const float* x  = (const float*)d_in[0];
    const float* W1 = (const float*)d_in[1];
    const float* b1 = (const float*)d_in[2];
    const float* W2 = (const float*)d_in[3];
    const float* b2 = (const float*)d_in[4];
    const float* W3 = (const float*)d_in[5];
    const float* b3 = (const float*)d_in[6];
    const float* Wc = (const float*)d_in[7];
    const float* bc = (const float*)d_in[8];
    const int*   ei = (const int*)d_in[9];

    const int N = in_sizes[0] / 3;
    const int E = in_sizes[9] / 2;
    const int G = out_size / 2;
    const int* src = ei;
    const int* dst = ei + E;

    char* ws = (char*)d_ws;
    size_t off_b = 0;
    auto alloc = [&](size_t bytes) {
        size_t o = off_b;
        off_b = (off_b + bytes + 255) & ~(size_t)255;
        return (void*)(ws + o);
    };
    float* dinv      = (float*)alloc((size_t)N * 4);
    int*   off       = (int*)alloc((size_t)(N + 1) * 4);
    int*   bucketCnt = (int*)alloc((NB_MAX + 1) * 4);
    int*   bucketOff = (int*)alloc((NB_MAX + 1) * 4);
    int*   bucketCur = (int*)alloc((NB_MAX + 1) * 4);
    int*   csr       = (int*)alloc((size_t)E * 4);
    float* xp        = (float*)alloc((size_t)N * 3 * 4);
    size_t bufA_sz   = (size_t)N * 64 * 4;
    if ((size_t)E * 4 > bufA_sz) bufA_sz = (size_t)E * 4;
    float* bufA      = (float*)alloc(bufA_sz);              // pairs -> G1 -> G2
    float* bufB      = (float*)alloc((size_t)N * 64 * 4);   // T1' -> T2' -> H

    unsigned* pairs = (unsigned*)bufA;
    float* G1 = bufA;
    float* G2 = bufA;
    unsigned short* T1 = (unsigned short*)bufB;
    unsigned short* T2 = (unsigned short*)bufB;
    float* H  = bufB;

    auto cdiv = [](long long a, long long b) { return (int)((a + b - 1) / b); };
    const int nb = cdiv(N, BKT_NODES);  // coarse buckets (<= NB_MAX)

    // ---- CSR build ----
    hipMemsetAsync(bucketCnt, 0, (size_t)nb * 4, stream);
    k_hist_coarse<<<1024, TPB, 0, stream>>>(dst, bucketCnt, E, nb);
    k_scanb<<<1, NB_MAX, 0, stream>>>(bucketCnt, bucketOff, bucketCur, off, nb, E, N);
    k_bin_pairs<<<cdiv(E, BIN_CHUNK), TPB, 0, stream>>>(src, dst, bucketCur, pairs, E, nb);
    k_bucket_csr<<<nb, BKT_NODES, 0, stream>>>(pairs, bucketOff, off, dinv, csr, N);

    // ---- layer 1 (fused): x' = dinv*x; T1' = dinv*relu(S'x'@W1+b1) ----
    k_scale3<<<cdiv((long long)N * 3, TPB), TPB, 0, stream>>>(x, dinv, xp, N * 3);
    k_g3mm1<<<cdiv(N, TPB), TPB, 0, stream>>>(off, csr, dinv, xp, W1, b1, T1, N);

    // ---- layer 2: G1 = dinv * (sum T1') ; T2' = dinv*relu(G1@W2+b2) ----
    k_gather32b<<<cdiv((long long)N * 64, TPB), TPB, 0, stream>>>(off, csr, dinv, T1, G1, N);
    k_mm2<<<cdiv(N, TPB), TPB, 0, stream>>>(G1, W2, b2, dinv, T2, N);

    // ---- layer 3: G2 = dinv * (sum T2') ; H = G2@W3+b3 ----
    k_gather64b<<<cdiv((long long)N * 64, TPB), TPB, 0, stream>>>(off, csr, dinv, T2, G2, N);
    k_mm3<<<cdiv(N, TPB), TPB, 0, stream>>>(G2, W3, b3, H, N);

    // ---- pool + classify + softmax ----
    k_pool<<<G, TPB, 0, stream>>>(H, Wc, bc, (float*)d_out, N, G);
}

// Round 7
// 307.624 us; speedup vs baseline: 7.0292x; 1.0520x over previous
//
#include <hip/hip_runtime.h>
#include <math.h>

#define TPB 256
#define TPB_H 512
#define TPB_BIN 1024
#define CSR_TPB 1024
#define NB_MAX 512      // coarse buckets of 256 nodes -> supports N <= 131072
#define BKT_SHIFT 8
#define BKT_NODES 256
#define BIN_CHUNK 8192

__device__ inline float bfLO(unsigned u) { return __uint_as_float(u << 16); }
__device__ inline float bfHI(unsigned u) { return __uint_as_float(u & 0xffff0000u); }
__device__ inline unsigned short f2bf(float f) {
    unsigned int x = __float_as_uint(f);
    return (unsigned short)((x + 0x7fffu + ((x >> 16) & 1u)) >> 16);  // RNE
}

// ---------------- pass A: coarse bucket histogram (LDS, int4 loads) ----------------
__global__ void k_hist_coarse(const int* __restrict__ dst, int* __restrict__ bucketCnt,
                              int e, int nb) {
    __shared__ int h[NB_MAX];
    for (int i = threadIdx.x; i < nb; i += TPB_H) h[i] = 0;
    __syncthreads();
    int e4 = e >> 2;
    const int4* d4 = (const int4*)dst;
    for (long long i = (long long)blockIdx.x * TPB_H + threadIdx.x; i < e4;
         i += (long long)gridDim.x * TPB_H) {
        int4 v = d4[i];
        atomicAdd(&h[v.x >> BKT_SHIFT], 1);
        atomicAdd(&h[v.y >> BKT_SHIFT], 1);
        atomicAdd(&h[v.z >> BKT_SHIFT], 1);
        atomicAdd(&h[v.w >> BKT_SHIFT], 1);
    }
    if (blockIdx.x == 0)
        for (int i = (e4 << 2) + threadIdx.x; i < e; i += TPB_H)
            atomicAdd(&h[dst[i] >> BKT_SHIFT], 1);
    __syncthreads();
    for (int i = threadIdx.x; i < nb; i += TPB_H)
        if (h[i]) atomicAdd(&bucketCnt[i], h[i]);
}

// ---------------- parallel bucket scan (1 block) ----------------
__global__ void k_scanb(const int* __restrict__ cnt, int* __restrict__ boff,
                        int* __restrict__ bcur, int* __restrict__ off_nodes,
                        int nb, int e, int n) {
    __shared__ int lds[NB_MAX];
    int t = threadIdx.x;
    int v = (t < nb) ? cnt[t] : 0;
    lds[t] = v;
    __syncthreads();
    for (int d = 1; d < NB_MAX; d <<= 1) {
        int x = (t >= d) ? lds[t - d] : 0;
        __syncthreads();
        lds[t] += x;
        __syncthreads();
    }
    int excl = lds[t] - v;
    if (t < nb) { boff[t] = excl; bcur[t] = excl; }
    if (t == nb - 1) boff[nb] = lds[t];
    if (t == 0) off_nodes[n] = e;
}

// ---------------- pass B: bin packed (src | local_dst<<24) by coarse bucket ----------------
__global__ void k_bin_pairs(const int* __restrict__ src, const int* __restrict__ dst,
                            int* __restrict__ bucketCur, unsigned* __restrict__ pairs,
                            int e, int nb) {
    __shared__ int h[NB_MAX];
    __shared__ int base[NB_MAX];
    int e0 = blockIdx.x * BIN_CHUNK;
    int e1 = min(e0 + BIN_CHUNK, e);
    for (int i = threadIdx.x; i < nb; i += TPB_BIN) h[i] = 0;
    __syncthreads();
    for (int i = e0 + threadIdx.x; i < e1; i += TPB_BIN)
        atomicAdd(&h[dst[i] >> BKT_SHIFT], 1);
    __syncthreads();
    for (int i = threadIdx.x; i < nb; i += TPB_BIN) {
        int c = h[i];
        base[i] = c ? atomicAdd(&bucketCur[i], c) : 0;
        h[i] = 0;  // reuse as intra-block cursor
    }
    __syncthreads();
    for (int i = e0 + threadIdx.x; i < e1; i += TPB_BIN) {
        int d = dst[i];
        int b = d >> BKT_SHIFT;
        int pos = base[b] + atomicAdd(&h[b], 1);
        pairs[pos] = ((unsigned)(d & (BKT_NODES - 1)) << 24) | (unsigned)src[i];
    }
}

// ---------------- pass C: per-bucket fine CSR + node offsets + dinv ----------------
__global__ void k_bucket_csr(const unsigned* __restrict__ pairs, const int* __restrict__ bucketOff,
                             int* __restrict__ off_nodes, float* __restrict__ dinv,
                             int* __restrict__ csr, int n) {
    __shared__ int hist[BKT_NODES];
    __shared__ int offl[BKT_NODES];
    __shared__ int cur[BKT_NODES];
    int b = blockIdx.x;
    int t = threadIdx.x;  // CSR_TPB threads
    int e0 = bucketOff[b], e1 = bucketOff[b + 1];
    int nbase = b << BKT_SHIFT;
    if (t < BKT_NODES) hist[t] = 0;
    __syncthreads();
    for (int e = e0 + t; e < e1; e += CSR_TPB)
        atomicAdd(&hist[pairs[e] >> 24], 1);
    __syncthreads();
    int v = 0;
    if (t < BKT_NODES) { v = hist[t]; offl[t] = v; }
    __syncthreads();
    for (int d = 1; d < BKT_NODES; d <<= 1) {
        int x = 0;
        if (t < BKT_NODES && t >= d) x = offl[t - d];
        __syncthreads();
        if (t < BKT_NODES) offl[t] += x;
        __syncthreads();
    }
    if (t < BKT_NODES) {
        int excl = offl[t] - v;
        cur[t] = excl;
        int nd = nbase + t;
        if (nd < n) {
            off_nodes[nd] = e0 + excl;
            dinv[nd] = rsqrtf((float)(v + 1));  // +1 self loop
        }
    }
    __syncthreads();
    for (int e = e0 + t; e < e1; e += CSR_TPB) {
        unsigned p = pairs[e];
        int l = (int)(p >> 24);
        int pos = e0 + atomicAdd(&cur[l], 1);
        csr[pos] = (int)(p & 0xffffffu);
    }
}

// ---------------- x' = dinv * x ----------------
__global__ void k_scale3(const float* __restrict__ x, const float* __restrict__ dinv,
                         float* __restrict__ xp, int n3) {
    int t = blockIdx.x * TPB + threadIdx.x;
    if (t >= n3) return;
    xp[t] = x[t] * dinv[t / 3];
}

// ---------------- fused gather(F=3) + mm1 + relu -> T1' = dinv*h1 (bf16) ----------------
__global__ void k_g3mm1(const int* __restrict__ off, const int* __restrict__ csr,
                        const float* __restrict__ dinv, const float* __restrict__ xp,
                        const float* __restrict__ W1, const float* __restrict__ b1,
                        unsigned short* __restrict__ T1, int n) {
    __shared__ float w1s[96];
    __shared__ float b1s[32];
    if (threadIdx.x < 96) w1s[threadIdx.x] = W1[threadIdx.x];
    if (threadIdx.x < 32) b1s[threadIdx.x] = b1[threadIdx.x];
    __syncthreads();
    int i = blockIdx.x * TPB + threadIdx.x;
    if (i >= n) return;
    float s0 = xp[i * 3], s1 = xp[i * 3 + 1], s2 = xp[i * 3 + 2];  // self (pre-scaled)
    int e = off[i], e1 = off[i + 1];
    for (; e + 3 < e1; e += 4) {
        int sa = csr[e], sb = csr[e + 1], sc = csr[e + 2], sd = csr[e + 3];
        float a0 = xp[sa * 3], a1 = xp[sa * 3 + 1], a2 = xp[sa * 3 + 2];
        float c0 = xp[sb * 3], c1 = xp[sb * 3 + 1], c2 = xp[sb * 3 + 2];
        float d0 = xp[sc * 3], d1 = xp[sc * 3 + 1], d2 = xp[sc * 3 + 2];
        float f0 = xp[sd * 3], f1 = xp[sd * 3 + 1], f2 = xp[sd * 3 + 2];
        s0 += a0 + c0 + d0 + f0;
        s1 += a1 + c1 + d1 + f1;
        s2 += a2 + c2 + d2 + f2;
    }
    for (; e < e1; ++e) {
        int s = csr[e];
        s0 += xp[s * 3]; s1 += xp[s * 3 + 1]; s2 += xp[s * 3 + 2];
    }
    float di = dinv[i];
    s0 *= di; s1 *= di; s2 *= di;   // Xa row
    unsigned outw[16];
#pragma unroll
    for (int fp = 0; fp < 16; fp++) {
        float h0 = fmaf(s0, w1s[2 * fp], fmaf(s1, w1s[32 + 2 * fp], fmaf(s2, w1s[64 + 2 * fp], b1s[2 * fp])));
        float h1 = fmaf(s0, w1s[2 * fp + 1], fmaf(s1, w1s[32 + 2 * fp + 1], fmaf(s2, w1s[64 + 2 * fp + 1], b1s[2 * fp + 1])));
        h0 = fmaxf(h0, 0.0f) * di;
        h1 = fmaxf(h1, 0.0f) * di;
        outw[fp] = (unsigned)f2bf(h0) | ((unsigned)f2bf(h1) << 16);
    }
    uint4* o = (uint4*)(T1 + (size_t)i * 32);
    o[0] = make_uint4(outw[0], outw[1], outw[2], outw[3]);
    o[1] = make_uint4(outw[4], outw[5], outw[6], outw[7]);
    o[2] = make_uint4(outw[8], outw[9], outw[10], outw[11]);
    o[3] = make_uint4(outw[12], outw[13], outw[14], outw[15]);
}

#define ACC8(v) do { \
    a0 += bfLO((v).x); a1 += bfHI((v).x); a2 += bfLO((v).y); a3 += bfHI((v).y); \
    a4 += bfLO((v).z); a5 += bfHI((v).z); a6 += bfLO((v).w); a7 += bfHI((v).w); } while (0)

// ---------------- gather F=32 (T pre-scaled bf16): 4 lanes/edge, 16 edges/iter ----------------
__global__ void k_gather32b(const int* __restrict__ off, const int* __restrict__ csr,
                            const float* __restrict__ dinv, const unsigned short* __restrict__ T,
                            float* __restrict__ G, int n) {
    int w = (blockIdx.x * TPB + threadIdx.x) >> 6;
    if (w >= n) return;
    int lane = threadIdx.x & 63;
    int grp = lane >> 2, q = lane & 3;   // feats q*8..q*8+7
    float a0 = 0, a1 = 0, a2 = 0, a3 = 0, a4 = 0, a5 = 0, a6 = 0, a7 = 0;
    if (grp == 0) {
        uint4 v = *(const uint4*)(T + ((size_t)w << 5) + (q << 3));
        ACC8(v);  // self (pre-scaled by dinv[w])
    }
    int e = off[w] + grp, e1 = off[w + 1];
    for (; e + 16 < e1; e += 32) {
        int s0 = csr[e], s1 = csr[e + 16];
        uint4 v0 = *(const uint4*)(T + ((size_t)s0 << 5) + (q << 3));
        uint4 v1 = *(const uint4*)(T + ((size_t)s1 << 5) + (q << 3));
        ACC8(v0); ACC8(v1);
    }
    if (e < e1) {
        int s = csr[e];
        uint4 v = *(const uint4*)(T + ((size_t)s << 5) + (q << 3));
        ACC8(v);
    }
#pragma unroll
    for (int m = 4; m < 64; m <<= 1) {
        a0 += __shfl_xor(a0, m); a1 += __shfl_xor(a1, m);
        a2 += __shfl_xor(a2, m); a3 += __shfl_xor(a3, m);
        a4 += __shfl_xor(a4, m); a5 += __shfl_xor(a5, m);
        a6 += __shfl_xor(a6, m); a7 += __shfl_xor(a7, m);
    }
    if (grp == 0) {
        float di = dinv[w];
        float* g = G + ((size_t)w << 5) + (q << 3);
        *(float4*)g = make_float4(a0 * di, a1 * di, a2 * di, a3 * di);
        *(float4*)(g + 4) = make_float4(a4 * di, a5 * di, a6 * di, a7 * di);
    }
}

// ---------------- mm2: one node per lane; T2' = dinv*relu(G1@W2+b2) bf16 ----------------
__global__ void k_mm2(const float* __restrict__ G, const float* __restrict__ W,
                      const float* __restrict__ b, const float* __restrict__ dinv,
                      unsigned short* __restrict__ T, int n) {
    int i = blockIdx.x * TPB + threadIdx.x;
    if (i >= n) return;
    float gr[32];
    const float4* g4 = (const float4*)(G + (size_t)i * 32);
#pragma unroll
    for (int c = 0; c < 8; c++) {
        float4 v = g4[c];
        gr[4 * c] = v.x; gr[4 * c + 1] = v.y; gr[4 * c + 2] = v.z; gr[4 * c + 3] = v.w;
    }
    float di = dinv[i];
    uint2* o = (uint2*)(T + (size_t)i * 64);
    for (int fc = 0; fc < 16; fc++) {  // output chunks of 4
        const float* bb = b + 4 * fc;
        float a0 = bb[0], a1 = bb[1], a2 = bb[2], a3 = bb[3];
#pragma unroll
        for (int k = 0; k < 32; k++) {
            const float* wr = W + k * 64 + 4 * fc;  // wave-uniform address
            float g = gr[k];
            a0 = fmaf(g, wr[0], a0);
            a1 = fmaf(g, wr[1], a1);
            a2 = fmaf(g, wr[2], a2);
            a3 = fmaf(g, wr[3], a3);
        }
        a0 = fmaxf(a0, 0.0f) * di; a1 = fmaxf(a1, 0.0f) * di;
        a2 = fmaxf(a2, 0.0f) * di; a3 = fmaxf(a3, 0.0f) * di;
        o[fc] = make_uint2((unsigned)f2bf(a0) | ((unsigned)f2bf(a1) << 16),
                           (unsigned)f2bf(a2) | ((unsigned)f2bf(a3) << 16));
    }
}

// ---------------- gather F=64 (T pre-scaled bf16): 8 lanes/edge, 4-deep (32 rows in flight) ----------------
__global__ void k_gather64b(const int* __restrict__ off, const int* __restrict__ csr,
                            const float* __restrict__ dinv, const unsigned short* __restrict__ T,
                            float* __restrict__ G, int n) {
    int w = (blockIdx.x * TPB + threadIdx.x) >> 6;
    if (w >= n) return;
    int lane = threadIdx.x & 63;
    int grp = lane >> 3, q = lane & 7;   // feats q*8..q*8+7
    float a0 = 0, a1 = 0, a2 = 0, a3 = 0, a4 = 0, a5 = 0, a6 = 0, a7 = 0;
    if (grp == 0) {
        uint4 v = *(const uint4*)(T + ((size_t)w << 6) + (q << 3));
        ACC8(v);  // self
    }
    int e = off[w] + grp, e1 = off[w + 1];
    for (; e + 24 < e1; e += 32) {
        int s0 = csr[e], s1 = csr[e + 8], s2 = csr[e + 16], s3 = csr[e + 24];
        uint4 v0 = *(const uint4*)(T + ((size_t)s0 << 6) + (q << 3));
        uint4 v1 = *(const uint4*)(T + ((size_t)s1 << 6) + (q << 3));
        uint4 v2 = *(const uint4*)(T + ((size_t)s2 << 6) + (q << 3));
        uint4 v3 = *(const uint4*)(T + ((size_t)s3 << 6) + (q << 3));
        ACC8(v0); ACC8(v1); ACC8(v2); ACC8(v3);
    }
    for (; e < e1; e += 8) {
        int s = csr[e];
        uint4 v = *(const uint4*)(T + ((size_t)s << 6) + (q << 3));
        ACC8(v);
    }
#pragma unroll
    for (int m = 8; m < 64; m <<= 1) {
        a0 += __shfl_xor(a0, m); a1 += __shfl_xor(a1, m);
        a2 += __shfl_xor(a2, m); a3 += __shfl_xor(a3, m);
        a4 += __shfl_xor(a4, m); a5 += __shfl_xor(a5, m);
        a6 += __shfl_xor(a6, m); a7 += __shfl_xor(a7, m);
    }
    if (grp == 0) {
        float di = dinv[w];
        float* g = G + ((size_t)w << 6) + (q << 3);
        *(float4*)g = make_float4(a0 * di, a1 * di, a2 * di, a3 * di);
        *(float4*)(g + 4) = make_float4(a4 * di, a5 * di, a6 * di, a7 * di);
    }
}

// ---------------- mm3: one node per lane; H = G2@W3 + b3 (fp32, no relu) ----------------
__global__ void k_mm3(const float* __restrict__ G, const float* __restrict__ W,
                      const float* __restrict__ b, float* __restrict__ H, int n) {
    int i = blockIdx.x * TPB + threadIdx.x;
    if (i >= n) return;
    float gr[64];
    const float4* g4 = (const float4*)(G + (size_t)i * 64);
#pragma unroll
    for (int c = 0; c < 16; c++) {
        float4 v = g4[c];
        gr[4 * c] = v.x; gr[4 * c + 1] = v.y; gr[4 * c + 2] = v.z; gr[4 * c + 3] = v.w;
    }
    float4* h4 = (float4*)(H + (size_t)i * 64);
    for (int fc = 0; fc < 16; fc++) {  // output chunks of 4
        const float* bb = b + 4 * fc;
        float a0 = bb[0], a1 = bb[1], a2 = bb[2], a3 = bb[3];
#pragma unroll
        for (int k = 0; k < 64; k++) {
            const float* wr = W + k * 64 + 4 * fc;  // wave-uniform address
            float g = gr[k];
            a0 = fmaf(g, wr[0], a0);
            a1 = fmaf(g, wr[1], a1);
            a2 = fmaf(g, wr[2], a2);
            a3 = fmaf(g, wr[3], a3);
        }
        h4[fc] = make_float4(a0, a1, a2, a3);
    }
}

// ---------------- pool (max & mean per graph) + classifier + softmax ----------------
__global__ void k_pool(const float* __restrict__ H, const float* __restrict__ Wc,
                       const float* __restrict__ bc, float* __restrict__ out,
                       int n, int g_total) {
    int g = blockIdx.x;
    int f = threadIdx.x & 63;
    int c = threadIdx.x >> 6;  // 0..3 chunks
    long long start = ((long long)g * n + g_total - 1) / g_total;
    long long end = ((long long)(g + 1) * n + g_total - 1) / g_total;
    float mx = -INFINITY, sm = 0.0f;
    for (long long i = start + c; i < end; i += 4) {
        float v = H[(i << 6) | f];
        mx = fmaxf(mx, v);
        sm += v;
    }
    __shared__ float smax[4][64], ssum[4][64], slog[2];
    smax[c][f] = mx; ssum[c][f] = sm;
    __syncthreads();
    if (c == 0) {
        mx = fmaxf(fmaxf(smax[0][f], smax[1][f]), fmaxf(smax[2][f], smax[3][f]));
        sm = ssum[0][f] + ssum[1][f] + ssum[2][f] + ssum[3][f];
        long long cnt = end - start;
        smax[0][f] = mx;
        ssum[0][f] = sm / (float)(cnt > 0 ? cnt : 1);
    }
    __syncthreads();
    if (threadIdx.x < 2) {
        int cls = threadIdx.x;
        float l = bc[cls];
        for (int k = 0; k < 64; k++)
            l += smax[0][k] * Wc[k * 2 + cls] + ssum[0][k] * Wc[(64 + k) * 2 + cls];
        slog[cls] = l;
    }
    __syncthreads();
    if (threadIdx.x == 0) {
        float m = fmaxf(slog[0], slog[1]);
        float e0 = expf(slog[0] - m), e1 = expf(slog[1] - m);
        float inv = 1.0f / (e0 + e1);
        out[g * 2 + 0] = e0 * inv;
        out[g * 2 + 1] = e1 * inv;
    }
}

extern "C" void kernel_launch(void* const* d_in, const int* in_sizes, int n_in,
                              void* d_out, int out_size, void* d_ws, size_t ws_size,
                              hipStream_t stream) {
    const float* x  = (const float*)d_in[0];
    const float* W1 = (const float*)d_in[1];
    const float* b1 = (const float*)d_in[2];
    const float* W2 = (const float*)d_in[3];
    const float* b2 = (const float*)d_in[4];
    const float* W3 = (const float*)d_in[5];
    const float* b3 = (const float*)d_in[6];
    const float* Wc = (const float*)d_in[7];
    const float* bc = (const float*)d_in[8];
    const int*   ei = (const int*)d_in[9];

    const int N = in_sizes[0] / 3;
    const int E = in_sizes[9] / 2;
    const int G = out_size / 2;
    const int* src = ei;
    const int* dst = ei + E;

    char* ws = (char*)d_ws;
    size_t off_b = 0;
    auto alloc = [&](size_t bytes) {
        size_t o = off_b;
        off_b = (off_b + bytes + 255) & ~(size_t)255;
        return (void*)(ws + o);
    };
    float* dinv      = (float*)alloc((size_t)N * 4);
    int*   off       = (int*)alloc((size_t)(N + 1) * 4);
    int*   bucketCnt = (int*)alloc((NB_MAX + 1) * 4);
    int*   bucketOff = (int*)alloc((NB_MAX + 1) * 4);
    int*   bucketCur = (int*)alloc((NB_MAX + 1) * 4);
    int*   csr       = (int*)alloc((size_t)E * 4);
    float* xp        = (float*)alloc((size_t)N * 3 * 4);
    size_t bufA_sz   = (size_t)N * 64 * 4;
    if ((size_t)E * 4 > bufA_sz) bufA_sz = (size_t)E * 4;
    float* bufA      = (float*)alloc(bufA_sz);              // pairs -> G1 -> G2
    float* bufB      = (float*)alloc((size_t)N * 64 * 4);   // T1' -> T2' -> H

    unsigned* pairs = (unsigned*)bufA;
    float* G1 = bufA;
    float* G2 = bufA;
    unsigned short* T1 = (unsigned short*)bufB;
    unsigned short* T2 = (unsigned short*)bufB;
    float* H  = bufB;

    auto cdiv = [](long long a, long long b) { return (int)((a + b - 1) / b); };
    const int nb = cdiv(N, BKT_NODES);  // coarse buckets (<= NB_MAX)

    // ---- CSR build ----
    hipMemsetAsync(bucketCnt, 0, (size_t)nb * 4, stream);
    k_hist_coarse<<<1024, TPB_H, 0, stream>>>(dst, bucketCnt, E, nb);
    k_scanb<<<1, NB_MAX, 0, stream>>>(bucketCnt, bucketOff, bucketCur, off, nb, E, N);
    k_bin_pairs<<<cdiv(E, BIN_CHUNK), TPB_BIN, 0, stream>>>(src, dst, bucketCur, pairs, E, nb);
    k_bucket_csr<<<nb, CSR_TPB, 0, stream>>>(pairs, bucketOff, off, dinv, csr, N);

    // ---- layer 1 (fused): x' = dinv*x; T1' = dinv*relu(S'x'@W1+b1) ----
    k_scale3<<<cdiv((long long)N * 3, TPB), TPB, 0, stream>>>(x, dinv, xp, N * 3);
    k_g3mm1<<<cdiv(N, TPB), TPB, 0, stream>>>(off, csr, dinv, xp, W1, b1, T1, N);

    // ---- layer 2: G1 = dinv * (sum T1') ; T2' = dinv*relu(G1@W2+b2) ----
    k_gather32b<<<cdiv((long long)N * 64, TPB), TPB, 0, stream>>>(off, csr, dinv, T1, G1, N);
    k_mm2<<<cdiv(N, TPB), TPB, 0, stream>>>(G1, W2, b2, dinv, T2, N);

    // ---- layer 3: G2 = dinv * (sum T2') ; H = G2@W3+b3 ----
    k_gather64b<<<cdiv((long long)N * 64, TPB), TPB, 0, stream>>>(off, csr, dinv, T2, G2, N);
    k_mm3<<<cdiv(N, TPB), TPB, 0, stream>>>(G2, W3, b3, H, N);

    // ---- pool + classify + softmax ----
    k_pool<<<G, TPB, 0, stream>>>(H, Wc, bc, (float*)d_out, N, G);
}